// Round 12
// baseline (677.243 us; speedup 1.0000x reference)
//
#include <hip/hip_runtime.h>
#include <hip/hip_bf16.h>
#include <cstdint>

// GAT 3-layer pipeline, MI355X. B=4, N=2048, Fin=128, nhid=64, H=8, emb=64, nclass=16.
// fp32 tensors; d_out = [image_feature (4*2048*64) | pre (4*16)] fp32.
// Round 12: attn_k widened to 1024 threads (4 row-waves x 4 kb-quarters, 72 KB LDS,
// launch_bounds(1024,8)) -> 512 blocks x 2/CU = 32 waves/CU (r11 was 16: block-count
// bound). combine_k fused into layer3a (img buffer deleted). Numerics unchanged.

#define NN 2048

typedef float f32x4 __attribute__((ext_vector_type(4)));
typedef __bf16 bf16x8 __attribute__((ext_vector_type(8)));
typedef _Float16 f16;
typedef _Float16 f16x8 __attribute__((ext_vector_type(8)));

__device__ __forceinline__ void gll16(const void* g, void* l) {
  __builtin_amdgcn_global_load_lds(
      (const __attribute__((address_space(1))) unsigned int*)g,
      (__attribute__((address_space(3))) unsigned int*)l, 16, 0, 0);
}

// ---------------- fused prep: adj->u8 kb-tiled plane, Ws/W1 -> bf16 hi/lo frags ----
// pm layout: [kb(64)][i(2048)][jb(32)] u8 (0xFF if edge) — 4 MB, tiles contiguous.
__global__ __launch_bounds__(256) void prep_k(
    const int* __restrict__ adj, unsigned char* __restrict__ pm,
    const float* __restrict__ Ws, __bf16* __restrict__ WsFh, __bf16* __restrict__ WsFl,
    const float* __restrict__ W1, __bf16* __restrict__ W1Fh, __bf16* __restrict__ W1Fl) {
  const int bx = blockIdx.x, t = threadIdx.x;
  if (bx < 2048) {
    const int i = bx;
#pragma unroll
    for (int jt = 0; jt < 8; ++jt) {
      const int j = jt * 256 + t;
      pm[((long)(j >> 5) << 16) + i * 32 + (j & 31)] =
          adj[(long)i * NN + j] > 0 ? 0xFFu : 0u;
    }
  } else if (bx < 2304) {
    const int idx = (bx - 2048) * 256 + t;  // 8 inst x 8192
    const int inst = idx >> 13;
    const int rem = idx & 8191;
    const int k = rem >> 6, n = rem & 63;
    const float v = Ws[(long)inst * 8192 + rem];
    const __bf16 vh = (__bf16)v;
    const int pos = ((k >> 5) * 4 + (n >> 4)) * 512 + (((k >> 3) & 3) * 16 + (n & 15)) * 8 + (k & 7);
    WsFh[(long)inst * 8192 + pos] = vh;
    WsFl[(long)inst * 8192 + pos] = (__bf16)(v - (float)vh);
  } else {
    const int idx = (bx - 2304) * 256 + t;  // 512 x 64
    const int k = idx >> 6, n = idx & 63;
    const float v = W1[idx];
    const __bf16 vh = (__bf16)v;
    const int pos = ((k >> 5) * 4 + (n >> 4)) * 512 + (((k >> 3) & 3) * 16 + (n & 15)) * 8 + (k & 7);
    W1Fh[pos] = vh;
    W1Fl[pos] = (__bf16)(v - (float)vh);
  }
}

// ---------------- MFMA GEMM (M rows, N=64). 128 thr, 32 rows/block. ----------------
struct GemmLd {
  float4 a0, a1;
  bf16x8 bh[4], bl[4];
};

__global__ __launch_bounds__(128) void gemm_mfma_k(
    const float* __restrict__ Aall, const __bf16* __restrict__ WFhi,
    const __bf16* __restrict__ WFlo, const float* __restrict__ avecAll,
    f16* __restrict__ WhBAll, float* __restrict__ Eo, float* __restrict__ Go,
    f16* __restrict__ Fo, f16* __restrict__ Ho, float* __restrict__ pC,
    int K, int KS, long aStrideB) {
  const int p = blockIdx.y;
  const int ks = blockIdx.z;
  const float* A = Aall + (long)(p & 3) * aStrideB;
  const long wfOff = (long)(p >> 2) * K * 64;
  const bf16x8* BhF = (const bf16x8*)(WFhi + wfOff);
  const bf16x8* BlF = (const bf16x8*)(WFlo + wfOff);

  const int t = threadIdx.x, lane = t & 63, wave = t >> 6;
  const int quad = lane >> 4, lm = lane & 15;
  const int i0w = blockIdx.x * 32 + wave * 16;
  const float* Arow = A + (long)(i0w + lm) * K;
  const int kBeg = ks * (K / KS), kEnd = kBeg + K / KS;

  f32x4 acc[4];
#pragma unroll
  for (int nt = 0; nt < 4; ++nt) acc[nt] = (f32x4){0.f, 0.f, 0.f, 0.f};

  auto LOAD = [&](GemmLd& L, int k0) {
    L.a0 = *(const float4*)(Arow + k0 + quad * 8);
    L.a1 = *(const float4*)(Arow + k0 + quad * 8 + 4);
    const int bbase = (k0 >> 5) * 256 + lane;
#pragma unroll
    for (int nt = 0; nt < 4; ++nt) {
      L.bh[nt] = BhF[bbase + nt * 64];
      L.bl[nt] = BlF[bbase + nt * 64];
    }
  };
  auto STEP = [&](const GemmLd& L) {
    const float av8[8] = {L.a0.x, L.a0.y, L.a0.z, L.a0.w, L.a1.x, L.a1.y, L.a1.z, L.a1.w};
    bf16x8 ah, al;
#pragma unroll
    for (int j = 0; j < 8; ++j) {
      const __bf16 h = (__bf16)av8[j];
      ah[j] = h;
      al[j] = (__bf16)(av8[j] - (float)h);
    }
#pragma unroll
    for (int nt = 0; nt < 4; ++nt) {
      acc[nt] = __builtin_amdgcn_mfma_f32_16x16x32_bf16(ah, L.bh[nt], acc[nt], 0, 0, 0);
      acc[nt] = __builtin_amdgcn_mfma_f32_16x16x32_bf16(al, L.bh[nt], acc[nt], 0, 0, 0);
      acc[nt] = __builtin_amdgcn_mfma_f32_16x16x32_bf16(ah, L.bl[nt], acc[nt], 0, 0, 0);
    }
  };

  GemmLd La, Lb;
  LOAD(La, kBeg);
  for (int k0 = kBeg; k0 < kEnd; k0 += 64) {
    LOAD(Lb, k0 + 32);
    STEP(La);
    LOAD(La, (k0 + 64 < kEnd) ? k0 + 64 : kBeg);
    STEP(Lb);
  }

  if (KS > 1) {
    float* pc = pC + ((long)(p * KS + ks) * NN) * 64;
#pragma unroll
    for (int reg = 0; reg < 4; ++reg) {
      const int row = i0w + quad * 4 + reg;
#pragma unroll
      for (int nt = 0; nt < 4; ++nt) pc[(long)row * 64 + nt * 16 + lm] = acc[nt][reg];
    }
    return;
  }

  const float* av = avecAll + (long)(p >> 2) * 128;
  f16* WhB = WhBAll + (long)p * NN * 64;
  float* E = Eo + (long)p * NN;
  float* G = Go + (long)p * NN;
  f16* F = Fo + (long)p * NN;
  f16* Hh = Ho + (long)p * NN;

  float alo[4], ahi[4];
#pragma unroll
  for (int nt = 0; nt < 4; ++nt) {
    alo[nt] = av[nt * 16 + lm];
    ahi[nt] = av[64 + nt * 16 + lm];
  }
#pragma unroll
  for (int reg = 0; reg < 4; ++reg) {
    float es = 0.f, ed = 0.f;
#pragma unroll
    for (int nt = 0; nt < 4; ++nt) {
      es += acc[nt][reg] * alo[nt];
      ed += acc[nt][reg] * ahi[nt];
    }
#pragma unroll
    for (int m = 1; m < 16; m <<= 1) {
      es += __shfl_xor(es, m);
      ed += __shfl_xor(ed, m);
    }
    if (lm == 0) {
      const int r = i0w + quad * 4 + reg;
      E[r] = __expf(es);
      G[r] = __expf(0.2f * es);
      F[r] = (f16)__expf(ed);
      Hh[r] = (f16)__expf(0.2f * ed);
    }
  }

  const int r0 = i0w + quad * 4;
  const long base = ((long)(r0 >> 5) * 4) * 512 + (((r0 >> 3) & 3) * 16 + lm) * 8 + (r0 & 7);
#pragma unroll
  for (int nt = 0; nt < 4; ++nt) {
    union { f16 h[4]; uint2 u; } pk;
#pragma unroll
    for (int q = 0; q < 4; ++q) pk.h[q] = (f16)acc[nt][q];
    *(uint2*)(WhB + base + nt * 512) = pk.u;
  }
}

// ---------------- layer-2 GEMM epilogue: sum KS partials -> E/G/F/H + WhB f16 ----
__global__ __launch_bounds__(256) void gemm_epi_k(
    const float* __restrict__ pC, const float* __restrict__ avec,
    f16* __restrict__ WhBAll, float* __restrict__ Eo, float* __restrict__ Go,
    f16* __restrict__ Fo, f16* __restrict__ Ho, int KS) {
  const int inst = blockIdx.y;
  const int t = threadIdx.x;
  const int row = blockIdx.x * 16 + (t >> 4);
  const int cg = t & 15;
  f32x4 c = (f32x4){0.f, 0.f, 0.f, 0.f};
  for (int ks = 0; ks < KS; ++ks)
    c += *(const f32x4*)(pC + (((long)(inst * KS + ks) * NN) + row) * 64 + cg * 4);
  float es = 0.f, ed = 0.f;
#pragma unroll
  for (int q = 0; q < 4; ++q) {
    const int n = cg * 4 + q;
    es += c[q] * avec[n];
    ed += c[q] * avec[64 + n];
  }
#pragma unroll
  for (int m = 1; m < 16; m <<= 1) {
    es += __shfl_xor(es, m);
    ed += __shfl_xor(ed, m);
  }
  if (cg == 0) {
    Eo[(long)inst * NN + row] = __expf(es);
    Go[(long)inst * NN + row] = __expf(0.2f * es);
    Fo[(long)inst * NN + row] = (f16)__expf(ed);
    Ho[(long)inst * NN + row] = (f16)__expf(0.2f * ed);
  }
  f16* WhB = WhBAll + (long)inst * NN * 64;
#pragma unroll
  for (int q = 0; q < 4; ++q) {
    const int n = cg * 4 + q;
    const int pos = ((row >> 5) * 4 + (n >> 4)) * 512 + (((row >> 3) & 3) * 16 + (n & 15)) * 8 + (row & 7);
    WhB[pos] = (f16)c[q];
  }
}

// ---------------- attention: LDS-staged tiles, fp16 P-gen, f16 MFMA, 16 waves ------
// 1024 thr = 16 waves: rw = wave&3 (32 rows each, block = 128 rows), q = wave>>2
// (kb-quarter). Wave rw==0 of each quarter stages its B (4KB) + mask (4KB) tiles via
// global_load_lds, double-buffered; 1 barrier/iter; 3-round LDS combine of quarters.
__global__ __launch_bounds__(1024, 8) void attn_k(
    const f16* __restrict__ WhBAll, const float* __restrict__ Eb,
    const float* __restrict__ Gb, const f16* __restrict__ Fb,
    const f16* __restrict__ Hb, const unsigned char* __restrict__ pm,
    float* __restrict__ out1, int rowStride, long strideB,
    int jsCount, float* __restrict__ partAcc, float* __restrict__ partSum) {
  const int p = blockIdx.z;
  const int js = blockIdx.y;
  const f16* WhB = WhBAll + (long)p * NN * 64;
  const float* E = Eb + (long)p * NN;
  const float* G = Gb + (long)p * NN;
  const f16* F = Fb + (long)p * NN;
  const f16* Hv = Hb + (long)p * NN;
  const int t = threadIdx.x, lane = t & 63, wave = t >> 6;
  const int rw = wave & 3, q = wave >> 2;
  const int quad = lane >> 4, lm = lane & 15;
  const int i0 = blockIdx.x * 128;
  const int rbase = rw * 32;
  const int span = 64 / jsCount;
  const int nIter = span / 4;
  const int kbBeg = js * span + q * nIter;

  // LDS pool: [0,4K) F, [4K,8K) H, [8K,72K) rings (q*16K + slot*8K: B 4K | M 4K).
  __shared__ __align__(16) char pool[73728];
  f16* Fs = (f16*)pool;
  f16* Hs = (f16*)(pool + 4096);
  char* ring = pool + 8192 + q * 16384;

  const int r0g = i0 + rbase + lm, r1g = i0 + rbase + 16 + lm;
  const f16 e0 = (f16)E[r0g], g0 = (f16)G[r0g];
  const f16 e1 = (f16)E[r1g], g1 = (f16)G[r1g];
  f16x8 e0v, g0v, e1v, g1v;
#pragma unroll
  for (int j = 0; j < 8; ++j) { e0v[j] = e0; g0v[j] = g0; e1v[j] = e1; g1v[j] = g1; }

  f16x8 ones;
#pragma unroll
  for (int j = 0; j < 8; ++j) ones[j] = (lm == 0) ? (f16)1.0f : (f16)0.0f;

  // prologue staging
  if (wave == 0) {
#pragma unroll
    for (int c = 0; c < 4; ++c) gll16((const char*)F + c * 1024 + lane * 16, pool + c * 1024);
  } else if (wave == 1) {
#pragma unroll
    for (int c = 0; c < 4; ++c) gll16((const char*)Hv + c * 1024 + lane * 16, pool + 4096 + c * 1024);
  }
  if (rw == 0) {
    const char* gB = (const char*)WhB + (long)kbBeg * 4096;
    const unsigned char* gM = pm + ((long)kbBeg << 16) + i0 * 32;
#pragma unroll
    for (int c = 0; c < 4; ++c) gll16(gB + c * 1024 + lane * 16, ring + c * 1024);
#pragma unroll
    for (int c = 0; c < 4; ++c) gll16(gM + c * 1024 + lane * 16, ring + 4096 + c * 1024);
  }
  __syncthreads();

  f32x4 acc0[4], acc1[4], sum0, sum1;
#pragma unroll
  for (int nt = 0; nt < 4; ++nt) {
    acc0[nt] = (f32x4){0.f, 0.f, 0.f, 0.f};
    acc1[nt] = (f32x4){0.f, 0.f, 0.f, 0.f};
  }
  sum0 = (f32x4){0.f, 0.f, 0.f, 0.f};
  sum1 = (f32x4){0.f, 0.f, 0.f, 0.f};

  for (int i = 0; i < nIter; ++i) {
    const int kb = kbBeg + i;
    if (rw == 0 && i + 1 < nIter) {
      char* dst = ring + ((i + 1) & 1) * 8192;
      const char* gB = (const char*)WhB + (long)(kb + 1) * 4096;
      const unsigned char* gM = pm + ((long)(kb + 1) << 16) + i0 * 32;
#pragma unroll
      for (int c = 0; c < 4; ++c) gll16(gB + c * 1024 + lane * 16, dst + c * 1024);
#pragma unroll
      for (int c = 0; c < 4; ++c) gll16(gM + c * 1024 + lane * 16, dst + 4096 + c * 1024);
    }
    const char* slot = ring + (i & 1) * 8192;
    const f16x8 F8 = *(const f16x8*)(Fs + kb * 32 + quad * 8);
    const f16x8 H8 = *(const f16x8*)(Hs + kb * 32 + quad * 8);
    const uint2 m0 = *(const uint2*)(slot + 4096 + (rbase + lm) * 32 + quad * 8);
    const uint2 m1 = *(const uint2*)(slot + 4096 + (rbase + 16 + lm) * 32 + quad * 8);

    union { f16x8 v; uint4 u; } A0, A1;
    A0.v = __builtin_elementwise_max(e0v * F8, g0v * H8);
    A1.v = __builtin_elementwise_max(e1v * F8, g1v * H8);
    A0.u.x &= __builtin_amdgcn_perm(0u, m0.x, 0x01010000u);
    A0.u.y &= __builtin_amdgcn_perm(0u, m0.x, 0x03030202u);
    A0.u.z &= __builtin_amdgcn_perm(0u, m0.y, 0x01010000u);
    A0.u.w &= __builtin_amdgcn_perm(0u, m0.y, 0x03030202u);
    A1.u.x &= __builtin_amdgcn_perm(0u, m1.x, 0x01010000u);
    A1.u.y &= __builtin_amdgcn_perm(0u, m1.x, 0x03030202u);
    A1.u.z &= __builtin_amdgcn_perm(0u, m1.y, 0x01010000u);
    A1.u.w &= __builtin_amdgcn_perm(0u, m1.y, 0x03030202u);

#pragma unroll
    for (int nt = 0; nt < 4; ++nt) {
      const f16x8 bfr = *(const f16x8*)(slot + (nt * 64 + lane) * 16);
      acc0[nt] = __builtin_amdgcn_mfma_f32_16x16x32_f16(A0.v, bfr, acc0[nt], 0, 0, 0);
      acc1[nt] = __builtin_amdgcn_mfma_f32_16x16x32_f16(A1.v, bfr, acc1[nt], 0, 0, 0);
    }
    sum0 = __builtin_amdgcn_mfma_f32_16x16x32_f16(A0.v, ones, sum0, 0, 0, 0);
    sum1 = __builtin_amdgcn_mfma_f32_16x16x32_f16(A1.v, ones, sum1, 0, 0, 0);
    __syncthreads();
  }

  // ---- 3-round LDS combine of the 4 quarters (set = 4rw x 64 lanes x 40 f32) ----
  float* cmb = (float*)pool;
#pragma unroll
  for (int r = 1; r < 4; ++r) {
    if (q == r) {
      float* dst = &cmb[(rw * 64 + lane) * 40];
#pragma unroll
      for (int nt = 0; nt < 4; ++nt) {
        *(f32x4*)(dst + nt * 4) = acc0[nt];
        *(f32x4*)(dst + 16 + nt * 4) = acc1[nt];
      }
      *(f32x4*)(dst + 32) = sum0;
      *(f32x4*)(dst + 36) = sum1;
    }
    __syncthreads();
    if (q == 0) {
      const float* src = &cmb[(rw * 64 + lane) * 40];
#pragma unroll
      for (int nt = 0; nt < 4; ++nt) {
        acc0[nt] += *(const f32x4*)(src + nt * 4);
        acc1[nt] += *(const f32x4*)(src + 16 + nt * 4);
      }
      sum0 += *(const f32x4*)(src + 32);
      sum1 += *(const f32x4*)(src + 36);
    }
    if (r < 3) __syncthreads();
  }
  if (q != 0) return;

  if (jsCount == 1) {
#pragma unroll
    for (int g = 0; g < 2; ++g) {
      const f32x4* acc = g ? acc1 : acc0;
      const f32x4 sm = g ? sum1 : sum0;
#pragma unroll
      for (int reg = 0; reg < 4; ++reg) {
        const int row = i0 + rbase + g * 16 + quad * 4 + reg;
        const float ls = __shfl(sm[reg], quad * 16);
        const float il = ls > 0.f ? 1.f / ls : 0.f;
#pragma unroll
        for (int nt = 0; nt < 4; ++nt) {
          float v = acc[nt][reg] * il;
          v = v > 0.f ? v : expm1f(v);  // elu
          const long o = (long)(p & 3) * strideB + (long)row * rowStride + (p >> 2) * 64 + nt * 16 + lm;
          out1[o] = v;
        }
      }
    }
  } else {
    float* pAcc = partAcc + ((long)p * jsCount + js) * NN * 64;
    float* pSum = partSum + ((long)p * jsCount + js) * NN;
#pragma unroll
    for (int g = 0; g < 2; ++g) {
      const f32x4* acc = g ? acc1 : acc0;
      const f32x4 sm = g ? sum1 : sum0;
#pragma unroll
      for (int reg = 0; reg < 4; ++reg) {
        const int row = i0 + rbase + g * 16 + quad * 4 + reg;
#pragma unroll
        for (int nt = 0; nt < 4; ++nt) pAcc[(long)row * 64 + nt * 16 + lm] = acc[nt][reg];
        if (lm == 0) pSum[row] = sm[reg];
      }
    }
  }
}

// ---------------- layer-3a: fused js-combine + elu + image_feature store + partials ----
// grid (B, 8). Each thread owns row j = chunk*256+t: combines JS partials, normalizes,
// elu -> writes image_feature; then layer-3 row-0-attention partial sums.
__global__ __launch_bounds__(256) void layer3a_k(
    const float* __restrict__ partAcc, const float* __restrict__ partSum,
    const float* __restrict__ W2, const float* __restrict__ a2,
    const unsigned char* __restrict__ pm, float* __restrict__ outImg,
    float* __restrict__ pOut /* [B][8][17] */, int JS) {
  const int bb = blockIdx.x, chunk = blockIdx.y, t = threadIdx.x;
  __shared__ float w2alo[64], w2ahi[64];
  __shared__ float W2s[64][17];
  __shared__ float v0[64];
  __shared__ float redc[4][17];
  if (t < 64) {
    float sl = 0.f, sh = 0.f;
#pragma unroll
    for (int c = 0; c < 16; ++c) {
      const float wv = W2[t * 16 + c];
      W2s[t][c] = wv;
      sl += wv * a2[c];
      sh += wv * a2[16 + c];
    }
    w2alo[t] = sl;
    w2ahi[t] = sh;
    // combined row 0, column t (broadcast loads)
    float s = 0.f, l0 = 0.f;
    for (int js = 0; js < JS; ++js) {
      const long b = ((long)bb * JS + js) * NN;
      s += partAcc[b * 64 + t];
      l0 += partSum[b];
    }
    float v = s * (l0 > 0.f ? 1.f / l0 : 0.f);
    v0[t] = v > 0.f ? v : expm1f(v);
  }
  __syncthreads();

  float es = 0.f;
#pragma unroll 16
  for (int k = 0; k < 64; ++k) es += v0[k] * w2alo[k];

  const int j = chunk * 256 + t;
  // combine row j across JS partials, normalize + elu
  float arow[64];
  {
    f32x4 v[16];
#pragma unroll
    for (int qq = 0; qq < 16; ++qq) v[qq] = (f32x4){0.f, 0.f, 0.f, 0.f};
    float s = 0.f;
    for (int js = 0; js < JS; ++js) {
      const long b = ((long)bb * JS + js) * NN;
      const float* src = partAcc + (b + j) * 64;
#pragma unroll
      for (int qq = 0; qq < 16; ++qq) v[qq] += *(const f32x4*)(src + qq * 4);
      s += partSum[b + j];
    }
    const float il = s > 0.f ? 1.f / s : 0.f;
    float* orow = outImg + ((long)bb * NN + j) * 64;
#pragma unroll
    for (int qq = 0; qq < 16; ++qq) {
      f32x4 r;
#pragma unroll
      for (int u = 0; u < 4; ++u) {
        float x = v[qq][u] * il;
        r[u] = x > 0.f ? x : expm1f(x);
        arow[qq * 4 + u] = r[u];
      }
      *(f32x4*)(orow + qq * 4) = r;
    }
  }

  float ed = 0.f;
#pragma unroll
  for (int k = 0; k < 64; ++k) ed += arow[k] * w2ahi[k];
  float e = es + ed;
  e = fmaxf(e, 0.2f * e);
  const float pv = pm[((long)(j >> 5) << 16) + (j & 31)] ? __expf(e) : 0.f;  // row 0 mask

  float acc[16];
#pragma unroll
  for (int c = 0; c < 16; ++c) {
    float wh = 0.f;
#pragma unroll
    for (int k = 0; k < 64; ++k) wh += arow[k] * W2s[k][c];
    acc[c] = pv * wh;
  }
  float lsum = pv;

#pragma unroll
  for (int off = 32; off > 0; off >>= 1) {
    lsum += __shfl_down(lsum, off);
#pragma unroll
    for (int c = 0; c < 16; ++c) acc[c] += __shfl_down(acc[c], off);
  }
  if ((t & 63) == 0) {
    const int wv = t >> 6;
#pragma unroll
    for (int c = 0; c < 16; ++c) redc[wv][c] = acc[c];
    redc[wv][16] = lsum;
  }
  __syncthreads();
  if (t < 17) {
    pOut[((long)bb * 8 + chunk) * 17 + t] =
        redc[0][t] + redc[1][t] + redc[2][t] + redc[3][t];
  }
}

// ---------------- layer-3b: sum 8 chunks, normalize + elu ----------------
__global__ __launch_bounds__(64) void layer3b_k(const float* __restrict__ pOut,
                                                float* __restrict__ outPre) {
  const int t = threadIdx.x;
  if (t >= 64) return;
  const int bb = t >> 4, c = t & 15;
  float a = 0.f, l = 0.f;
#pragma unroll
  for (int ch = 0; ch < 8; ++ch) {
    a += pOut[((long)bb * 8 + ch) * 17 + c];
    l += pOut[((long)bb * 8 + ch) * 17 + 16];
  }
  float v = a / l;
  v = v > 0.f ? v : expm1f(v);
  outPre[bb * 16 + c] = v;
}

// ---------------- host ----------------
extern "C" void kernel_launch(void* const* d_in, const int* in_sizes, int n_in,
                              void* d_out, int out_size, void* d_ws, size_t ws_size,
                              hipStream_t stream) {
  (void)in_sizes; (void)n_in; (void)out_size; (void)ws_size;
  constexpr int B = 4, N = NN, JS2 = 4, KS2 = 4;

  const float* slices = (const float*)d_in[0];
  const int* adj = (const int*)d_in[1];
  const float* Ws = (const float*)d_in[2];
  const float* As = (const float*)d_in[3];
  const float* W1 = (const float*)d_in[4];
  const float* a1 = (const float*)d_in[5];
  const float* W2 = (const float*)d_in[6];
  const float* a2 = (const float*)d_in[7];
  float* out = (float*)d_out;

  char* w = (char*)d_ws;
  size_t off = 0;
  auto alloc = [&](size_t bytes) {
    void* ptr = w + off;
    off += (bytes + 255) & ~(size_t)255;
    return ptr;
  };
  unsigned char* pm = (unsigned char*)alloc((size_t)64 * 65536);  // 4 MB kb-tiled mask
  __bf16* WsFh = (__bf16*)alloc((size_t)8 * 128 * 64 * 2);
  __bf16* WsFl = (__bf16*)alloc((size_t)8 * 128 * 64 * 2);
  __bf16* W1Fh = (__bf16*)alloc((size_t)512 * 64 * 2);
  __bf16* W1Fl = (__bf16*)alloc((size_t)512 * 64 * 2);
  f16* WhB1 = (f16*)alloc((size_t)32 * N * 64 * 2);  // 8 MB
  float* E1 = (float*)alloc((size_t)32 * N * 4);
  float* G1 = (float*)alloc((size_t)32 * N * 4);
  f16* F1 = (f16*)alloc((size_t)32 * N * 2);
  f16* H1 = (f16*)alloc((size_t)32 * N * 2);
  float* x = (float*)alloc((size_t)B * N * 512 * 4);  // 16 MB
  float* pC2 = (float*)alloc((size_t)B * KS2 * N * 64 * 4);  // 8 MB
  f16* WhB2 = (f16*)alloc((size_t)B * N * 64 * 2);
  float* E2 = (float*)alloc((size_t)B * N * 4);
  float* G2 = (float*)alloc((size_t)B * N * 4);
  f16* F2 = (f16*)alloc((size_t)B * N * 2);
  f16* H2 = (f16*)alloc((size_t)B * N * 2);
  float* pAcc2 = (float*)alloc((size_t)B * JS2 * N * 64 * 4);  // 8 MB
  float* pSum2 = (float*)alloc((size_t)B * JS2 * N * 4);
  float* pL3 = (float*)alloc((size_t)B * 8 * 17 * 4);

  prep_k<<<dim3(2432), dim3(256), 0, stream>>>(adj, pm, Ws, WsFh, WsFl, W1, W1Fh, W1Fl);

  // layer 1
  gemm_mfma_k<<<dim3(N / 32, 32, 1), dim3(128), 0, stream>>>(
      slices, WsFh, WsFl, As, WhB1, E1, G1, F1, H1, (float*)nullptr,
      128, 1, (long)N * 128);
  attn_k<<<dim3(N / 128, 1, 32), dim3(1024), 0, stream>>>(
      WhB1, E1, G1, F1, H1, pm, x, 512, (long)N * 512,
      1, (float*)nullptr, (float*)nullptr);

  // layer 2
  gemm_mfma_k<<<dim3(N / 32, 4, KS2), dim3(128), 0, stream>>>(
      x, W1Fh, W1Fl, a1, (f16*)nullptr, (float*)nullptr, (float*)nullptr,
      (f16*)nullptr, (f16*)nullptr, pC2, 512, KS2, (long)N * 512);
  gemm_epi_k<<<dim3(N / 16, 4), dim3(256), 0, stream>>>(
      pC2, a1, WhB2, E2, G2, F2, H2, KS2);
  attn_k<<<dim3(N / 128, JS2, 4), dim3(1024), 0, stream>>>(
      WhB2, E2, G2, F2, H2, pm, (float*)nullptr, 64, (long)N * 64,
      JS2, pAcc2, pSum2);

  // layer 3 (fused combine + image_feature store) + reduce
  layer3a_k<<<dim3(B, 8), dim3(256), 0, stream>>>(
      pAcc2, pSum2, W2, a2, pm, out, pL3, JS2);
  layer3b_k<<<dim3(1), dim3(64), 0, stream>>>(pL3, out + (size_t)B * N * 64);
}

// Round 13
// 182.640 us; speedup vs baseline: 3.7081x; 3.7081x over previous
//
#include <hip/hip_runtime.h>
#include <hip/hip_bf16.h>
#include <cstdint>

// GAT 3-layer pipeline, MI355X. B=4, N=2048, Fin=128, nhid=64, H=8, emb=64, nclass=16.
// fp32 tensors; d_out = [image_feature (4*2048*64) | pre (4*16)] fp32.
// Round 13: r12 structure with the spill bug fixed — __launch_bounds__(1024, 4)
// (r12's ",8" forced a 64-VGPR budget -> allocator hit 32 -> 2 GB scratch spill traffic,
// 472us/dispatch). Per-wave state is ~52 VGPR (r10/r11 measured); 4 waves/EU = 128-VGPR
// budget, LDS (72KB -> 2 blocks/CU) still gives the intended 32 waves/CU.

#define NN 2048

typedef float f32x4 __attribute__((ext_vector_type(4)));
typedef __bf16 bf16x8 __attribute__((ext_vector_type(8)));
typedef _Float16 f16;
typedef _Float16 f16x8 __attribute__((ext_vector_type(8)));

__device__ __forceinline__ void gll16(const void* g, void* l) {
  __builtin_amdgcn_global_load_lds(
      (const __attribute__((address_space(1))) unsigned int*)g,
      (__attribute__((address_space(3))) unsigned int*)l, 16, 0, 0);
}

// ---------------- fused prep: adj->u8 kb-tiled plane, Ws/W1 -> bf16 hi/lo frags ----
// pm layout: [kb(64)][i(2048)][jb(32)] u8 (0xFF if edge) — 4 MB, tiles contiguous.
__global__ __launch_bounds__(256) void prep_k(
    const int* __restrict__ adj, unsigned char* __restrict__ pm,
    const float* __restrict__ Ws, __bf16* __restrict__ WsFh, __bf16* __restrict__ WsFl,
    const float* __restrict__ W1, __bf16* __restrict__ W1Fh, __bf16* __restrict__ W1Fl) {
  const int bx = blockIdx.x, t = threadIdx.x;
  if (bx < 2048) {
    const int i = bx;
#pragma unroll
    for (int jt = 0; jt < 8; ++jt) {
      const int j = jt * 256 + t;
      pm[((long)(j >> 5) << 16) + i * 32 + (j & 31)] =
          adj[(long)i * NN + j] > 0 ? 0xFFu : 0u;
    }
  } else if (bx < 2304) {
    const int idx = (bx - 2048) * 256 + t;  // 8 inst x 8192
    const int inst = idx >> 13;
    const int rem = idx & 8191;
    const int k = rem >> 6, n = rem & 63;
    const float v = Ws[(long)inst * 8192 + rem];
    const __bf16 vh = (__bf16)v;
    const int pos = ((k >> 5) * 4 + (n >> 4)) * 512 + (((k >> 3) & 3) * 16 + (n & 15)) * 8 + (k & 7);
    WsFh[(long)inst * 8192 + pos] = vh;
    WsFl[(long)inst * 8192 + pos] = (__bf16)(v - (float)vh);
  } else {
    const int idx = (bx - 2304) * 256 + t;  // 512 x 64
    const int k = idx >> 6, n = idx & 63;
    const float v = W1[idx];
    const __bf16 vh = (__bf16)v;
    const int pos = ((k >> 5) * 4 + (n >> 4)) * 512 + (((k >> 3) & 3) * 16 + (n & 15)) * 8 + (k & 7);
    W1Fh[pos] = vh;
    W1Fl[pos] = (__bf16)(v - (float)vh);
  }
}

// ---------------- MFMA GEMM (M rows, N=64). 128 thr, 32 rows/block. ----------------
struct GemmLd {
  float4 a0, a1;
  bf16x8 bh[4], bl[4];
};

__global__ __launch_bounds__(128) void gemm_mfma_k(
    const float* __restrict__ Aall, const __bf16* __restrict__ WFhi,
    const __bf16* __restrict__ WFlo, const float* __restrict__ avecAll,
    f16* __restrict__ WhBAll, float* __restrict__ Eo, float* __restrict__ Go,
    f16* __restrict__ Fo, f16* __restrict__ Ho, float* __restrict__ pC,
    int K, int KS, long aStrideB) {
  const int p = blockIdx.y;
  const int ks = blockIdx.z;
  const float* A = Aall + (long)(p & 3) * aStrideB;
  const long wfOff = (long)(p >> 2) * K * 64;
  const bf16x8* BhF = (const bf16x8*)(WFhi + wfOff);
  const bf16x8* BlF = (const bf16x8*)(WFlo + wfOff);

  const int t = threadIdx.x, lane = t & 63, wave = t >> 6;
  const int quad = lane >> 4, lm = lane & 15;
  const int i0w = blockIdx.x * 32 + wave * 16;
  const float* Arow = A + (long)(i0w + lm) * K;
  const int kBeg = ks * (K / KS), kEnd = kBeg + K / KS;

  f32x4 acc[4];
#pragma unroll
  for (int nt = 0; nt < 4; ++nt) acc[nt] = (f32x4){0.f, 0.f, 0.f, 0.f};

  auto LOAD = [&](GemmLd& L, int k0) {
    L.a0 = *(const float4*)(Arow + k0 + quad * 8);
    L.a1 = *(const float4*)(Arow + k0 + quad * 8 + 4);
    const int bbase = (k0 >> 5) * 256 + lane;
#pragma unroll
    for (int nt = 0; nt < 4; ++nt) {
      L.bh[nt] = BhF[bbase + nt * 64];
      L.bl[nt] = BlF[bbase + nt * 64];
    }
  };
  auto STEP = [&](const GemmLd& L) {
    const float av8[8] = {L.a0.x, L.a0.y, L.a0.z, L.a0.w, L.a1.x, L.a1.y, L.a1.z, L.a1.w};
    bf16x8 ah, al;
#pragma unroll
    for (int j = 0; j < 8; ++j) {
      const __bf16 h = (__bf16)av8[j];
      ah[j] = h;
      al[j] = (__bf16)(av8[j] - (float)h);
    }
#pragma unroll
    for (int nt = 0; nt < 4; ++nt) {
      acc[nt] = __builtin_amdgcn_mfma_f32_16x16x32_bf16(ah, L.bh[nt], acc[nt], 0, 0, 0);
      acc[nt] = __builtin_amdgcn_mfma_f32_16x16x32_bf16(al, L.bh[nt], acc[nt], 0, 0, 0);
      acc[nt] = __builtin_amdgcn_mfma_f32_16x16x32_bf16(ah, L.bl[nt], acc[nt], 0, 0, 0);
    }
  };

  GemmLd La, Lb;
  LOAD(La, kBeg);
  for (int k0 = kBeg; k0 < kEnd; k0 += 64) {
    LOAD(Lb, k0 + 32);
    STEP(La);
    LOAD(La, (k0 + 64 < kEnd) ? k0 + 64 : kBeg);
    STEP(Lb);
  }

  if (KS > 1) {
    float* pc = pC + ((long)(p * KS + ks) * NN) * 64;
#pragma unroll
    for (int reg = 0; reg < 4; ++reg) {
      const int row = i0w + quad * 4 + reg;
#pragma unroll
      for (int nt = 0; nt < 4; ++nt) pc[(long)row * 64 + nt * 16 + lm] = acc[nt][reg];
    }
    return;
  }

  const float* av = avecAll + (long)(p >> 2) * 128;
  f16* WhB = WhBAll + (long)p * NN * 64;
  float* E = Eo + (long)p * NN;
  float* G = Go + (long)p * NN;
  f16* F = Fo + (long)p * NN;
  f16* Hh = Ho + (long)p * NN;

  float alo[4], ahi[4];
#pragma unroll
  for (int nt = 0; nt < 4; ++nt) {
    alo[nt] = av[nt * 16 + lm];
    ahi[nt] = av[64 + nt * 16 + lm];
  }
#pragma unroll
  for (int reg = 0; reg < 4; ++reg) {
    float es = 0.f, ed = 0.f;
#pragma unroll
    for (int nt = 0; nt < 4; ++nt) {
      es += acc[nt][reg] * alo[nt];
      ed += acc[nt][reg] * ahi[nt];
    }
#pragma unroll
    for (int m = 1; m < 16; m <<= 1) {
      es += __shfl_xor(es, m);
      ed += __shfl_xor(ed, m);
    }
    if (lm == 0) {
      const int r = i0w + quad * 4 + reg;
      E[r] = __expf(es);
      G[r] = __expf(0.2f * es);
      F[r] = (f16)__expf(ed);
      Hh[r] = (f16)__expf(0.2f * ed);
    }
  }

  const int r0 = i0w + quad * 4;
  const long base = ((long)(r0 >> 5) * 4) * 512 + (((r0 >> 3) & 3) * 16 + lm) * 8 + (r0 & 7);
#pragma unroll
  for (int nt = 0; nt < 4; ++nt) {
    union { f16 h[4]; uint2 u; } pk;
#pragma unroll
    for (int q = 0; q < 4; ++q) pk.h[q] = (f16)acc[nt][q];
    *(uint2*)(WhB + base + nt * 512) = pk.u;
  }
}

// ---------------- layer-2 GEMM epilogue: sum KS partials -> E/G/F/H + WhB f16 ----
__global__ __launch_bounds__(256) void gemm_epi_k(
    const float* __restrict__ pC, const float* __restrict__ avec,
    f16* __restrict__ WhBAll, float* __restrict__ Eo, float* __restrict__ Go,
    f16* __restrict__ Fo, f16* __restrict__ Ho, int KS) {
  const int inst = blockIdx.y;
  const int t = threadIdx.x;
  const int row = blockIdx.x * 16 + (t >> 4);
  const int cg = t & 15;
  f32x4 c = (f32x4){0.f, 0.f, 0.f, 0.f};
  for (int ks = 0; ks < KS; ++ks)
    c += *(const f32x4*)(pC + (((long)(inst * KS + ks) * NN) + row) * 64 + cg * 4);
  float es = 0.f, ed = 0.f;
#pragma unroll
  for (int q = 0; q < 4; ++q) {
    const int n = cg * 4 + q;
    es += c[q] * avec[n];
    ed += c[q] * avec[64 + n];
  }
#pragma unroll
  for (int m = 1; m < 16; m <<= 1) {
    es += __shfl_xor(es, m);
    ed += __shfl_xor(ed, m);
  }
  if (cg == 0) {
    Eo[(long)inst * NN + row] = __expf(es);
    Go[(long)inst * NN + row] = __expf(0.2f * es);
    Fo[(long)inst * NN + row] = (f16)__expf(ed);
    Ho[(long)inst * NN + row] = (f16)__expf(0.2f * ed);
  }
  f16* WhB = WhBAll + (long)inst * NN * 64;
#pragma unroll
  for (int q = 0; q < 4; ++q) {
    const int n = cg * 4 + q;
    const int pos = ((row >> 5) * 4 + (n >> 4)) * 512 + (((row >> 3) & 3) * 16 + (n & 15)) * 8 + (row & 7);
    WhB[pos] = (f16)c[q];
  }
}

// ---------------- attention: LDS-staged tiles, fp16 P-gen, f16 MFMA, 16 waves ------
// 1024 thr = 16 waves: rw = wave&3 (32 rows each, block = 128 rows), q = wave>>2
// (kb-quarter). Wave rw==0 of each quarter stages its B (4KB) + mask (4KB) tiles via
// global_load_lds, double-buffered; 1 barrier/iter; 3-round LDS combine of quarters.
// launch_bounds(1024, 4): 128-VGPR budget (state ~52) — r12's ",8" caused scratch spill.
__global__ __launch_bounds__(1024, 4) void attn_k(
    const f16* __restrict__ WhBAll, const float* __restrict__ Eb,
    const float* __restrict__ Gb, const f16* __restrict__ Fb,
    const f16* __restrict__ Hb, const unsigned char* __restrict__ pm,
    float* __restrict__ out1, int rowStride, long strideB,
    int jsCount, float* __restrict__ partAcc, float* __restrict__ partSum) {
  const int p = blockIdx.z;
  const int js = blockIdx.y;
  const f16* WhB = WhBAll + (long)p * NN * 64;
  const float* E = Eb + (long)p * NN;
  const float* G = Gb + (long)p * NN;
  const f16* F = Fb + (long)p * NN;
  const f16* Hv = Hb + (long)p * NN;
  const int t = threadIdx.x, lane = t & 63, wave = t >> 6;
  const int rw = wave & 3, q = wave >> 2;
  const int quad = lane >> 4, lm = lane & 15;
  const int i0 = blockIdx.x * 128;
  const int rbase = rw * 32;
  const int span = 64 / jsCount;
  const int nIter = span / 4;
  const int kbBeg = js * span + q * nIter;

  // LDS pool: [0,4K) F, [4K,8K) H, [8K,72K) rings (q*16K + slot*8K: B 4K | M 4K).
  __shared__ __align__(16) char pool[73728];
  f16* Fs = (f16*)pool;
  f16* Hs = (f16*)(pool + 4096);
  char* ring = pool + 8192 + q * 16384;

  const int r0g = i0 + rbase + lm, r1g = i0 + rbase + 16 + lm;
  const f16 e0 = (f16)E[r0g], g0 = (f16)G[r0g];
  const f16 e1 = (f16)E[r1g], g1 = (f16)G[r1g];
  f16x8 e0v, g0v, e1v, g1v;
#pragma unroll
  for (int j = 0; j < 8; ++j) { e0v[j] = e0; g0v[j] = g0; e1v[j] = e1; g1v[j] = g1; }

  f16x8 ones;
#pragma unroll
  for (int j = 0; j < 8; ++j) ones[j] = (lm == 0) ? (f16)1.0f : (f16)0.0f;

  // prologue staging
  if (wave == 0) {
#pragma unroll
    for (int c = 0; c < 4; ++c) gll16((const char*)F + c * 1024 + lane * 16, pool + c * 1024);
  } else if (wave == 1) {
#pragma unroll
    for (int c = 0; c < 4; ++c) gll16((const char*)Hv + c * 1024 + lane * 16, pool + 4096 + c * 1024);
  }
  if (rw == 0) {
    const char* gB = (const char*)WhB + (long)kbBeg * 4096;
    const unsigned char* gM = pm + ((long)kbBeg << 16) + i0 * 32;
#pragma unroll
    for (int c = 0; c < 4; ++c) gll16(gB + c * 1024 + lane * 16, ring + c * 1024);
#pragma unroll
    for (int c = 0; c < 4; ++c) gll16(gM + c * 1024 + lane * 16, ring + 4096 + c * 1024);
  }
  __syncthreads();

  f32x4 acc0[4], acc1[4], sum0, sum1;
#pragma unroll
  for (int nt = 0; nt < 4; ++nt) {
    acc0[nt] = (f32x4){0.f, 0.f, 0.f, 0.f};
    acc1[nt] = (f32x4){0.f, 0.f, 0.f, 0.f};
  }
  sum0 = (f32x4){0.f, 0.f, 0.f, 0.f};
  sum1 = (f32x4){0.f, 0.f, 0.f, 0.f};

  for (int i = 0; i < nIter; ++i) {
    const int kb = kbBeg + i;
    if (rw == 0 && i + 1 < nIter) {
      char* dst = ring + ((i + 1) & 1) * 8192;
      const char* gB = (const char*)WhB + (long)(kb + 1) * 4096;
      const unsigned char* gM = pm + ((long)(kb + 1) << 16) + i0 * 32;
#pragma unroll
      for (int c = 0; c < 4; ++c) gll16(gB + c * 1024 + lane * 16, dst + c * 1024);
#pragma unroll
      for (int c = 0; c < 4; ++c) gll16(gM + c * 1024 + lane * 16, dst + 4096 + c * 1024);
    }
    const char* slot = ring + (i & 1) * 8192;
    const f16x8 F8 = *(const f16x8*)(Fs + kb * 32 + quad * 8);
    const f16x8 H8 = *(const f16x8*)(Hs + kb * 32 + quad * 8);
    const uint2 m0 = *(const uint2*)(slot + 4096 + (rbase + lm) * 32 + quad * 8);
    const uint2 m1 = *(const uint2*)(slot + 4096 + (rbase + 16 + lm) * 32 + quad * 8);

    union { f16x8 v; uint4 u; } A0, A1;
    A0.v = __builtin_elementwise_max(e0v * F8, g0v * H8);
    A1.v = __builtin_elementwise_max(e1v * F8, g1v * H8);
    A0.u.x &= __builtin_amdgcn_perm(0u, m0.x, 0x01010000u);
    A0.u.y &= __builtin_amdgcn_perm(0u, m0.x, 0x03030202u);
    A0.u.z &= __builtin_amdgcn_perm(0u, m0.y, 0x01010000u);
    A0.u.w &= __builtin_amdgcn_perm(0u, m0.y, 0x03030202u);
    A1.u.x &= __builtin_amdgcn_perm(0u, m1.x, 0x01010000u);
    A1.u.y &= __builtin_amdgcn_perm(0u, m1.x, 0x03030202u);
    A1.u.z &= __builtin_amdgcn_perm(0u, m1.y, 0x01010000u);
    A1.u.w &= __builtin_amdgcn_perm(0u, m1.y, 0x03030202u);

#pragma unroll
    for (int nt = 0; nt < 4; ++nt) {
      const f16x8 bfr = *(const f16x8*)(slot + (nt * 64 + lane) * 16);
      acc0[nt] = __builtin_amdgcn_mfma_f32_16x16x32_f16(A0.v, bfr, acc0[nt], 0, 0, 0);
      acc1[nt] = __builtin_amdgcn_mfma_f32_16x16x32_f16(A1.v, bfr, acc1[nt], 0, 0, 0);
    }
    sum0 = __builtin_amdgcn_mfma_f32_16x16x32_f16(A0.v, ones, sum0, 0, 0, 0);
    sum1 = __builtin_amdgcn_mfma_f32_16x16x32_f16(A1.v, ones, sum1, 0, 0, 0);
    __syncthreads();
  }

  // ---- 3-round LDS combine of the 4 quarters (set = 4rw x 64 lanes x 40 f32) ----
  float* cmb = (float*)pool;
#pragma unroll
  for (int r = 1; r < 4; ++r) {
    if (q == r) {
      float* dst = &cmb[(rw * 64 + lane) * 40];
#pragma unroll
      for (int nt = 0; nt < 4; ++nt) {
        *(f32x4*)(dst + nt * 4) = acc0[nt];
        *(f32x4*)(dst + 16 + nt * 4) = acc1[nt];
      }
      *(f32x4*)(dst + 32) = sum0;
      *(f32x4*)(dst + 36) = sum1;
    }
    __syncthreads();
    if (q == 0) {
      const float* src = &cmb[(rw * 64 + lane) * 40];
#pragma unroll
      for (int nt = 0; nt < 4; ++nt) {
        acc0[nt] += *(const f32x4*)(src + nt * 4);
        acc1[nt] += *(const f32x4*)(src + 16 + nt * 4);
      }
      sum0 += *(const f32x4*)(src + 32);
      sum1 += *(const f32x4*)(src + 36);
    }
    if (r < 3) __syncthreads();
  }
  if (q != 0) return;

  if (jsCount == 1) {
#pragma unroll
    for (int g = 0; g < 2; ++g) {
      const f32x4* acc = g ? acc1 : acc0;
      const f32x4 sm = g ? sum1 : sum0;
#pragma unroll
      for (int reg = 0; reg < 4; ++reg) {
        const int row = i0 + rbase + g * 16 + quad * 4 + reg;
        const float ls = __shfl(sm[reg], quad * 16);
        const float il = ls > 0.f ? 1.f / ls : 0.f;
#pragma unroll
        for (int nt = 0; nt < 4; ++nt) {
          float v = acc[nt][reg] * il;
          v = v > 0.f ? v : expm1f(v);  // elu
          const long o = (long)(p & 3) * strideB + (long)row * rowStride + (p >> 2) * 64 + nt * 16 + lm;
          out1[o] = v;
        }
      }
    }
  } else {
    float* pAcc = partAcc + ((long)p * jsCount + js) * NN * 64;
    float* pSum = partSum + ((long)p * jsCount + js) * NN;
#pragma unroll
    for (int g = 0; g < 2; ++g) {
      const f32x4* acc = g ? acc1 : acc0;
      const f32x4 sm = g ? sum1 : sum0;
#pragma unroll
      for (int reg = 0; reg < 4; ++reg) {
        const int row = i0 + rbase + g * 16 + quad * 4 + reg;
#pragma unroll
        for (int nt = 0; nt < 4; ++nt) pAcc[(long)row * 64 + nt * 16 + lm] = acc[nt][reg];
        if (lm == 0) pSum[row] = sm[reg];
      }
    }
  }
}

// ---------------- layer-3a: fused js-combine + elu + image_feature store + partials ----
__global__ __launch_bounds__(256) void layer3a_k(
    const float* __restrict__ partAcc, const float* __restrict__ partSum,
    const float* __restrict__ W2, const float* __restrict__ a2,
    const unsigned char* __restrict__ pm, float* __restrict__ outImg,
    float* __restrict__ pOut /* [B][8][17] */, int JS) {
  const int bb = blockIdx.x, chunk = blockIdx.y, t = threadIdx.x;
  __shared__ float w2alo[64], w2ahi[64];
  __shared__ float W2s[64][17];
  __shared__ float v0[64];
  __shared__ float redc[4][17];
  if (t < 64) {
    float sl = 0.f, sh = 0.f;
#pragma unroll
    for (int c = 0; c < 16; ++c) {
      const float wv = W2[t * 16 + c];
      W2s[t][c] = wv;
      sl += wv * a2[c];
      sh += wv * a2[16 + c];
    }
    w2alo[t] = sl;
    w2ahi[t] = sh;
    float s = 0.f, l0 = 0.f;
    for (int js = 0; js < JS; ++js) {
      const long b = ((long)bb * JS + js) * NN;
      s += partAcc[b * 64 + t];
      l0 += partSum[b];
    }
    float v = s * (l0 > 0.f ? 1.f / l0 : 0.f);
    v0[t] = v > 0.f ? v : expm1f(v);
  }
  __syncthreads();

  float es = 0.f;
#pragma unroll 16
  for (int k = 0; k < 64; ++k) es += v0[k] * w2alo[k];

  const int j = chunk * 256 + t;
  float arow[64];
  {
    f32x4 v[16];
#pragma unroll
    for (int qq = 0; qq < 16; ++qq) v[qq] = (f32x4){0.f, 0.f, 0.f, 0.f};
    float s = 0.f;
    for (int js = 0; js < JS; ++js) {
      const long b = ((long)bb * JS + js) * NN;
      const float* src = partAcc + (b + j) * 64;
#pragma unroll
      for (int qq = 0; qq < 16; ++qq) v[qq] += *(const f32x4*)(src + qq * 4);
      s += partSum[b + j];
    }
    const float il = s > 0.f ? 1.f / s : 0.f;
    float* orow = outImg + ((long)bb * NN + j) * 64;
#pragma unroll
    for (int qq = 0; qq < 16; ++qq) {
      f32x4 r;
#pragma unroll
      for (int u = 0; u < 4; ++u) {
        float x = v[qq][u] * il;
        r[u] = x > 0.f ? x : expm1f(x);
        arow[qq * 4 + u] = r[u];
      }
      *(f32x4*)(orow + qq * 4) = r;
    }
  }

  float ed = 0.f;
#pragma unroll
  for (int k = 0; k < 64; ++k) ed += arow[k] * w2ahi[k];
  float e = es + ed;
  e = fmaxf(e, 0.2f * e);
  const float pv = pm[((long)(j >> 5) << 16) + (j & 31)] ? __expf(e) : 0.f;  // row 0 mask

  float acc[16];
#pragma unroll
  for (int c = 0; c < 16; ++c) {
    float wh = 0.f;
#pragma unroll
    for (int k = 0; k < 64; ++k) wh += arow[k] * W2s[k][c];
    acc[c] = pv * wh;
  }
  float lsum = pv;

#pragma unroll
  for (int off = 32; off > 0; off >>= 1) {
    lsum += __shfl_down(lsum, off);
#pragma unroll
    for (int c = 0; c < 16; ++c) acc[c] += __shfl_down(acc[c], off);
  }
  if ((t & 63) == 0) {
    const int wv = t >> 6;
#pragma unroll
    for (int c = 0; c < 16; ++c) redc[wv][c] = acc[c];
    redc[wv][16] = lsum;
  }
  __syncthreads();
  if (t < 17) {
    pOut[((long)bb * 8 + chunk) * 17 + t] =
        redc[0][t] + redc[1][t] + redc[2][t] + redc[3][t];
  }
}

// ---------------- layer-3b: sum 8 chunks, normalize + elu ----------------
__global__ __launch_bounds__(64) void layer3b_k(const float* __restrict__ pOut,
                                                float* __restrict__ outPre) {
  const int t = threadIdx.x;
  if (t >= 64) return;
  const int bb = t >> 4, c = t & 15;
  float a = 0.f, l = 0.f;
#pragma unroll
  for (int ch = 0; ch < 8; ++ch) {
    a += pOut[((long)bb * 8 + ch) * 17 + c];
    l += pOut[((long)bb * 8 + ch) * 17 + 16];
  }
  float v = a / l;
  v = v > 0.f ? v : expm1f(v);
  outPre[bb * 16 + c] = v;
}

// ---------------- host ----------------
extern "C" void kernel_launch(void* const* d_in, const int* in_sizes, int n_in,
                              void* d_out, int out_size, void* d_ws, size_t ws_size,
                              hipStream_t stream) {
  (void)in_sizes; (void)n_in; (void)out_size; (void)ws_size;
  constexpr int B = 4, N = NN, JS2 = 4, KS2 = 4;

  const float* slices = (const float*)d_in[0];
  const int* adj = (const int*)d_in[1];
  const float* Ws = (const float*)d_in[2];
  const float* As = (const float*)d_in[3];
  const float* W1 = (const float*)d_in[4];
  const float* a1 = (const float*)d_in[5];
  const float* W2 = (const float*)d_in[6];
  const float* a2 = (const float*)d_in[7];
  float* out = (float*)d_out;

  char* w = (char*)d_ws;
  size_t off = 0;
  auto alloc = [&](size_t bytes) {
    void* ptr = w + off;
    off += (bytes + 255) & ~(size_t)255;
    return ptr;
  };
  unsigned char* pm = (unsigned char*)alloc((size_t)64 * 65536);  // 4 MB kb-tiled mask
  __bf16* WsFh = (__bf16*)alloc((size_t)8 * 128 * 64 * 2);
  __bf16* WsFl = (__bf16*)alloc((size_t)8 * 128 * 64 * 2);
  __bf16* W1Fh = (__bf16*)alloc((size_t)512 * 64 * 2);
  __bf16* W1Fl = (__bf16*)alloc((size_t)512 * 64 * 2);
  f16* WhB1 = (f16*)alloc((size_t)32 * N * 64 * 2);  // 8 MB
  float* E1 = (float*)alloc((size_t)32 * N * 4);
  float* G1 = (float*)alloc((size_t)32 * N * 4);
  f16* F1 = (f16*)alloc((size_t)32 * N * 2);
  f16* H1 = (f16*)alloc((size_t)32 * N * 2);
  float* x = (float*)alloc((size_t)B * N * 512 * 4);  // 16 MB
  float* pC2 = (float*)alloc((size_t)B * KS2 * N * 64 * 4);  // 8 MB
  f16* WhB2 = (f16*)alloc((size_t)B * N * 64 * 2);
  float* E2 = (float*)alloc((size_t)B * N * 4);
  float* G2 = (float*)alloc((size_t)B * N * 4);
  f16* F2 = (f16*)alloc((size_t)B * N * 2);
  f16* H2 = (f16*)alloc((size_t)B * N * 2);
  float* pAcc2 = (float*)alloc((size_t)B * JS2 * N * 64 * 4);  // 8 MB
  float* pSum2 = (float*)alloc((size_t)B * JS2 * N * 4);
  float* pL3 = (float*)alloc((size_t)B * 8 * 17 * 4);

  prep_k<<<dim3(2432), dim3(256), 0, stream>>>(adj, pm, Ws, WsFh, WsFl, W1, W1Fh, W1Fl);

  // layer 1
  gemm_mfma_k<<<dim3(N / 32, 32, 1), dim3(128), 0, stream>>>(
      slices, WsFh, WsFl, As, WhB1, E1, G1, F1, H1, (float*)nullptr,
      128, 1, (long)N * 128);
  attn_k<<<dim3(N / 128, 1, 32), dim3(1024), 0, stream>>>(
      WhB1, E1, G1, F1, H1, pm, x, 512, (long)N * 512,
      1, (float*)nullptr, (float*)nullptr);

  // layer 2
  gemm_mfma_k<<<dim3(N / 32, 4, KS2), dim3(128), 0, stream>>>(
      x, W1Fh, W1Fl, a1, (f16*)nullptr, (float*)nullptr, (float*)nullptr,
      (f16*)nullptr, (f16*)nullptr, pC2, 512, KS2, (long)N * 512);
  gemm_epi_k<<<dim3(N / 16, 4), dim3(256), 0, stream>>>(
      pC2, a1, WhB2, E2, G2, F2, H2, KS2);
  attn_k<<<dim3(N / 128, JS2, 4), dim3(1024), 0, stream>>>(
      WhB2, E2, G2, F2, H2, pm, (float*)nullptr, 64, (long)N * 64,
      JS2, pAcc2, pSum2);

  // layer 3 (fused combine + image_feature store) + reduce
  layer3a_k<<<dim3(B, 8), dim3(256), 0, stream>>>(
      pAcc2, pSum2, W2, a2, pm, out, pL3, JS2);
  layer3b_k<<<dim3(1), dim3(64), 0, stream>>>(pL3, out + (size_t)B * N * 64);
}

// Round 14
// 172.202 us; speedup vs baseline: 3.9329x; 1.0606x over previous
//
#include <hip/hip_runtime.h>
#include <hip/hip_bf16.h>
#include <cstdint>

// GAT 3-layer pipeline, MI355X. B=4, N=2048, Fin=128, nhid=64, H=8, emb=64, nclass=16.
// fp32 tensors; d_out = [image_feature (4*2048*64) | pre (4*16)] fp32.
// Round 14: attention back to the proven 512-thr/8-wave r11 structure (r13's 16-wave
// barrier was a net loss), with (a) masks read DIRECTLY from global (one wave's mask
// load is a contiguous 512B coalesced region; LDS staging of masks caused the 3.9e6
// 4-way bank conflicts and doubled staged bytes), and (b) 2 B-tiles staged per barrier
// (8KB slots; barrier count halved, 2 iterations of prefetch slack). LDS still 40KB.

#define NN 2048

typedef float f32x4 __attribute__((ext_vector_type(4)));
typedef __bf16 bf16x8 __attribute__((ext_vector_type(8)));
typedef _Float16 f16;
typedef _Float16 f16x8 __attribute__((ext_vector_type(8)));

__device__ __forceinline__ void gll16(const void* g, void* l) {
  __builtin_amdgcn_global_load_lds(
      (const __attribute__((address_space(1))) unsigned int*)g,
      (__attribute__((address_space(3))) unsigned int*)l, 16, 0, 0);
}

// ---------------- fused prep: adj->u8 kb-tiled plane, Ws/W1 -> bf16 hi/lo frags ----
// pm layout: [kb(64)][i(2048)][jb(32)] u8 (0xFF if edge) — 4 MB, tiles contiguous.
__global__ __launch_bounds__(256) void prep_k(
    const int* __restrict__ adj, unsigned char* __restrict__ pm,
    const float* __restrict__ Ws, __bf16* __restrict__ WsFh, __bf16* __restrict__ WsFl,
    const float* __restrict__ W1, __bf16* __restrict__ W1Fh, __bf16* __restrict__ W1Fl) {
  const int bx = blockIdx.x, t = threadIdx.x;
  if (bx < 2048) {
    const int i = bx;
#pragma unroll
    for (int jt = 0; jt < 8; ++jt) {
      const int j = jt * 256 + t;
      pm[((long)(j >> 5) << 16) + i * 32 + (j & 31)] =
          adj[(long)i * NN + j] > 0 ? 0xFFu : 0u;
    }
  } else if (bx < 2304) {
    const int idx = (bx - 2048) * 256 + t;  // 8 inst x 8192
    const int inst = idx >> 13;
    const int rem = idx & 8191;
    const int k = rem >> 6, n = rem & 63;
    const float v = Ws[(long)inst * 8192 + rem];
    const __bf16 vh = (__bf16)v;
    const int pos = ((k >> 5) * 4 + (n >> 4)) * 512 + (((k >> 3) & 3) * 16 + (n & 15)) * 8 + (k & 7);
    WsFh[(long)inst * 8192 + pos] = vh;
    WsFl[(long)inst * 8192 + pos] = (__bf16)(v - (float)vh);
  } else {
    const int idx = (bx - 2304) * 256 + t;  // 512 x 64
    const int k = idx >> 6, n = idx & 63;
    const float v = W1[idx];
    const __bf16 vh = (__bf16)v;
    const int pos = ((k >> 5) * 4 + (n >> 4)) * 512 + (((k >> 3) & 3) * 16 + (n & 15)) * 8 + (k & 7);
    W1Fh[pos] = vh;
    W1Fl[pos] = (__bf16)(v - (float)vh);
  }
}

// ---------------- MFMA GEMM (M rows, N=64). 128 thr, 32 rows/block. ----------------
struct GemmLd {
  float4 a0, a1;
  bf16x8 bh[4], bl[4];
};

__global__ __launch_bounds__(128) void gemm_mfma_k(
    const float* __restrict__ Aall, const __bf16* __restrict__ WFhi,
    const __bf16* __restrict__ WFlo, const float* __restrict__ avecAll,
    f16* __restrict__ WhBAll, float* __restrict__ Eo, float* __restrict__ Go,
    f16* __restrict__ Fo, f16* __restrict__ Ho, float* __restrict__ pC,
    int K, int KS, long aStrideB) {
  const int p = blockIdx.y;
  const int ks = blockIdx.z;
  const float* A = Aall + (long)(p & 3) * aStrideB;
  const long wfOff = (long)(p >> 2) * K * 64;
  const bf16x8* BhF = (const bf16x8*)(WFhi + wfOff);
  const bf16x8* BlF = (const bf16x8*)(WFlo + wfOff);

  const int t = threadIdx.x, lane = t & 63, wave = t >> 6;
  const int quad = lane >> 4, lm = lane & 15;
  const int i0w = blockIdx.x * 32 + wave * 16;
  const float* Arow = A + (long)(i0w + lm) * K;
  const int kBeg = ks * (K / KS), kEnd = kBeg + K / KS;

  f32x4 acc[4];
#pragma unroll
  for (int nt = 0; nt < 4; ++nt) acc[nt] = (f32x4){0.f, 0.f, 0.f, 0.f};

  auto LOAD = [&](GemmLd& L, int k0) {
    L.a0 = *(const float4*)(Arow + k0 + quad * 8);
    L.a1 = *(const float4*)(Arow + k0 + quad * 8 + 4);
    const int bbase = (k0 >> 5) * 256 + lane;
#pragma unroll
    for (int nt = 0; nt < 4; ++nt) {
      L.bh[nt] = BhF[bbase + nt * 64];
      L.bl[nt] = BlF[bbase + nt * 64];
    }
  };
  auto STEP = [&](const GemmLd& L) {
    const float av8[8] = {L.a0.x, L.a0.y, L.a0.z, L.a0.w, L.a1.x, L.a1.y, L.a1.z, L.a1.w};
    bf16x8 ah, al;
#pragma unroll
    for (int j = 0; j < 8; ++j) {
      const __bf16 h = (__bf16)av8[j];
      ah[j] = h;
      al[j] = (__bf16)(av8[j] - (float)h);
    }
#pragma unroll
    for (int nt = 0; nt < 4; ++nt) {
      acc[nt] = __builtin_amdgcn_mfma_f32_16x16x32_bf16(ah, L.bh[nt], acc[nt], 0, 0, 0);
      acc[nt] = __builtin_amdgcn_mfma_f32_16x16x32_bf16(al, L.bh[nt], acc[nt], 0, 0, 0);
      acc[nt] = __builtin_amdgcn_mfma_f32_16x16x32_bf16(ah, L.bl[nt], acc[nt], 0, 0, 0);
    }
  };

  GemmLd La, Lb;
  LOAD(La, kBeg);
  for (int k0 = kBeg; k0 < kEnd; k0 += 64) {
    LOAD(Lb, k0 + 32);
    STEP(La);
    LOAD(La, (k0 + 64 < kEnd) ? k0 + 64 : kBeg);
    STEP(Lb);
  }

  if (KS > 1) {
    float* pc = pC + ((long)(p * KS + ks) * NN) * 64;
#pragma unroll
    for (int reg = 0; reg < 4; ++reg) {
      const int row = i0w + quad * 4 + reg;
#pragma unroll
      for (int nt = 0; nt < 4; ++nt) pc[(long)row * 64 + nt * 16 + lm] = acc[nt][reg];
    }
    return;
  }

  const float* av = avecAll + (long)(p >> 2) * 128;
  f16* WhB = WhBAll + (long)p * NN * 64;
  float* E = Eo + (long)p * NN;
  float* G = Go + (long)p * NN;
  f16* F = Fo + (long)p * NN;
  f16* Hh = Ho + (long)p * NN;

  float alo[4], ahi[4];
#pragma unroll
  for (int nt = 0; nt < 4; ++nt) {
    alo[nt] = av[nt * 16 + lm];
    ahi[nt] = av[64 + nt * 16 + lm];
  }
#pragma unroll
  for (int reg = 0; reg < 4; ++reg) {
    float es = 0.f, ed = 0.f;
#pragma unroll
    for (int nt = 0; nt < 4; ++nt) {
      es += acc[nt][reg] * alo[nt];
      ed += acc[nt][reg] * ahi[nt];
    }
#pragma unroll
    for (int m = 1; m < 16; m <<= 1) {
      es += __shfl_xor(es, m);
      ed += __shfl_xor(ed, m);
    }
    if (lm == 0) {
      const int r = i0w + quad * 4 + reg;
      E[r] = __expf(es);
      G[r] = __expf(0.2f * es);
      F[r] = (f16)__expf(ed);
      Hh[r] = (f16)__expf(0.2f * ed);
    }
  }

  const int r0 = i0w + quad * 4;
  const long base = ((long)(r0 >> 5) * 4) * 512 + (((r0 >> 3) & 3) * 16 + lm) * 8 + (r0 & 7);
#pragma unroll
  for (int nt = 0; nt < 4; ++nt) {
    union { f16 h[4]; uint2 u; } pk;
#pragma unroll
    for (int q = 0; q < 4; ++q) pk.h[q] = (f16)acc[nt][q];
    *(uint2*)(WhB + base + nt * 512) = pk.u;
  }
}

// ---------------- layer-2 GEMM epilogue: sum KS partials -> E/G/F/H + WhB f16 ----
__global__ __launch_bounds__(256) void gemm_epi_k(
    const float* __restrict__ pC, const float* __restrict__ avec,
    f16* __restrict__ WhBAll, float* __restrict__ Eo, float* __restrict__ Go,
    f16* __restrict__ Fo, f16* __restrict__ Ho, int KS) {
  const int inst = blockIdx.y;
  const int t = threadIdx.x;
  const int row = blockIdx.x * 16 + (t >> 4);
  const int cg = t & 15;
  f32x4 c = (f32x4){0.f, 0.f, 0.f, 0.f};
  for (int ks = 0; ks < KS; ++ks)
    c += *(const f32x4*)(pC + (((long)(inst * KS + ks) * NN) + row) * 64 + cg * 4);
  float es = 0.f, ed = 0.f;
#pragma unroll
  for (int q = 0; q < 4; ++q) {
    const int n = cg * 4 + q;
    es += c[q] * avec[n];
    ed += c[q] * avec[64 + n];
  }
#pragma unroll
  for (int m = 1; m < 16; m <<= 1) {
    es += __shfl_xor(es, m);
    ed += __shfl_xor(ed, m);
  }
  if (cg == 0) {
    Eo[(long)inst * NN + row] = __expf(es);
    Go[(long)inst * NN + row] = __expf(0.2f * es);
    Fo[(long)inst * NN + row] = (f16)__expf(ed);
    Ho[(long)inst * NN + row] = (f16)__expf(0.2f * ed);
  }
  f16* WhB = WhBAll + (long)inst * NN * 64;
#pragma unroll
  for (int q = 0; q < 4; ++q) {
    const int n = cg * 4 + q;
    const int pos = ((row >> 5) * 4 + (n >> 4)) * 512 + (((row >> 3) & 3) * 16 + (n & 15)) * 8 + (row & 7);
    WhB[pos] = (f16)c[q];
  }
}

// ---------------- attention: LDS-staged B (2 tiles/barrier), global masks ----------
// 512 thr = 8 waves: rw = wave&3 (32 rows each, block = 128 rows), half = wave>>2
// (kb-half). Wave rw==0 of each half stages TWO 4KB B-tiles per step into an 8KB slot
// (double-buffered); masks are coalesced uint2 global loads (no LDS, no conflicts).
__global__ __launch_bounds__(512) void attn_k(
    const f16* __restrict__ WhBAll, const float* __restrict__ Eb,
    const float* __restrict__ Gb, const f16* __restrict__ Fb,
    const f16* __restrict__ Hb, const unsigned char* __restrict__ pm,
    float* __restrict__ out1, int rowStride, long strideB,
    int jsCount, float* __restrict__ partAcc, float* __restrict__ partSum) {
  const int p = blockIdx.z;
  const int js = blockIdx.y;
  const f16* WhB = WhBAll + (long)p * NN * 64;
  const float* E = Eb + (long)p * NN;
  const float* G = Gb + (long)p * NN;
  const f16* F = Fb + (long)p * NN;
  const f16* Hv = Hb + (long)p * NN;
  const int t = threadIdx.x, lane = t & 63, wave = t >> 6;
  const int rw = wave & 3, half = wave >> 2;
  const int quad = lane >> 4, lm = lane & 15;
  const int i0 = blockIdx.x * 128;
  const int rbase = rw * 32;
  const int span = 64 / jsCount;     // kb per js job
  const int nIter = span / 2;        // kb per half
  const int nStep = nIter / 2;       // 2 kb per step
  const int kbBeg = js * span + half * nIter;

  // LDS pool: [0,4K) F, [4K,8K) H, [8K,40K) rings (half*16K + slot*8K, slot = 2 B-tiles)
  // Combine phase overlays the whole pool (40 KB).
  __shared__ __align__(16) char pool[40960];
  f16* Fs = (f16*)pool;
  f16* Hs = (f16*)(pool + 4096);
  char* ring = pool + 8192 + half * 16384;

  const int r0g = i0 + rbase + lm, r1g = i0 + rbase + 16 + lm;
  const f16 e0 = (f16)E[r0g], g0 = (f16)G[r0g];
  const f16 e1 = (f16)E[r1g], g1 = (f16)G[r1g];
  f16x8 e0v, g0v, e1v, g1v;
#pragma unroll
  for (int j = 0; j < 8; ++j) { e0v[j] = e0; g0v[j] = g0; e1v[j] = e1; g1v[j] = g1; }

  f16x8 ones;
#pragma unroll
  for (int j = 0; j < 8; ++j) ones[j] = (lm == 0) ? (f16)1.0f : (f16)0.0f;

  // prologue staging: F/H (wave 0/1) + first 8KB B slot per half (rw==0 waves)
  if (wave == 0) {
#pragma unroll
    for (int c = 0; c < 4; ++c) gll16((const char*)F + c * 1024 + lane * 16, pool + c * 1024);
  } else if (wave == 1) {
#pragma unroll
    for (int c = 0; c < 4; ++c) gll16((const char*)Hv + c * 1024 + lane * 16, pool + 4096 + c * 1024);
  }
  if (rw == 0) {
    const char* gB = (const char*)WhB + (long)kbBeg * 4096;
#pragma unroll
    for (int c = 0; c < 8; ++c) gll16(gB + c * 1024 + lane * 16, ring + c * 1024);
  }
  __syncthreads();

  f32x4 acc0[4], acc1[4], sum0, sum1;
#pragma unroll
  for (int nt = 0; nt < 4; ++nt) {
    acc0[nt] = (f32x4){0.f, 0.f, 0.f, 0.f};
    acc1[nt] = (f32x4){0.f, 0.f, 0.f, 0.f};
  }
  sum0 = (f32x4){0.f, 0.f, 0.f, 0.f};
  sum1 = (f32x4){0.f, 0.f, 0.f, 0.f};

  const unsigned char* mp0 = pm + (long)(i0 + rbase + lm) * 32 + quad * 8;
  const unsigned char* mp1 = pm + (long)(i0 + rbase + 16 + lm) * 32 + quad * 8;

  for (int s = 0; s < nStep; ++s) {
    if (rw == 0 && s + 1 < nStep) {  // prefetch next 2 tiles into other slot
      char* dst = ring + ((s + 1) & 1) * 8192;
      const char* gB = (const char*)WhB + (long)(kbBeg + (s + 1) * 2) * 4096;
#pragma unroll
      for (int c = 0; c < 8; ++c) gll16(gB + c * 1024 + lane * 16, dst + c * 1024);
    }
    const char* slot = ring + (s & 1) * 8192;
#pragma unroll
    for (int u = 0; u < 2; ++u) {
      const int kb = kbBeg + s * 2 + u;
      const char* bt = slot + u * 4096;
      // masks: coalesced global loads (contiguous 512B per wave per load)
      const uint2 m0 = *(const uint2*)(mp0 + ((long)kb << 16));
      const uint2 m1 = *(const uint2*)(mp1 + ((long)kb << 16));
      const f16x8 F8 = *(const f16x8*)(Fs + kb * 32 + quad * 8);
      const f16x8 H8 = *(const f16x8*)(Hs + kb * 32 + quad * 8);

      union { f16x8 v; uint4 u4; } A0, A1;
      A0.v = __builtin_elementwise_max(e0v * F8, g0v * H8);
      A1.v = __builtin_elementwise_max(e1v * F8, g1v * H8);
      A0.u4.x &= __builtin_amdgcn_perm(0u, m0.x, 0x01010000u);
      A0.u4.y &= __builtin_amdgcn_perm(0u, m0.x, 0x03030202u);
      A0.u4.z &= __builtin_amdgcn_perm(0u, m0.y, 0x01010000u);
      A0.u4.w &= __builtin_amdgcn_perm(0u, m0.y, 0x03030202u);
      A1.u4.x &= __builtin_amdgcn_perm(0u, m1.x, 0x01010000u);
      A1.u4.y &= __builtin_amdgcn_perm(0u, m1.x, 0x03030202u);
      A1.u4.z &= __builtin_amdgcn_perm(0u, m1.y, 0x01010000u);
      A1.u4.w &= __builtin_amdgcn_perm(0u, m1.y, 0x03030202u);

#pragma unroll
      for (int nt = 0; nt < 4; ++nt) {
        const f16x8 bfr = *(const f16x8*)(bt + (nt * 64 + lane) * 16);
        acc0[nt] = __builtin_amdgcn_mfma_f32_16x16x32_f16(A0.v, bfr, acc0[nt], 0, 0, 0);
        acc1[nt] = __builtin_amdgcn_mfma_f32_16x16x32_f16(A1.v, bfr, acc1[nt], 0, 0, 0);
      }
      sum0 = __builtin_amdgcn_mfma_f32_16x16x32_f16(A0.v, ones, sum0, 0, 0, 0);
      sum1 = __builtin_amdgcn_mfma_f32_16x16x32_f16(A1.v, ones, sum1, 0, 0, 0);
    }
    __syncthreads();
  }

  // ---- combine the two kb-halves via LDS (overlay pool) ----
  float* cmb = (float*)pool;
  if (half == 1) {
    float* dst = &cmb[(rw * 64 + lane) * 40];
#pragma unroll
    for (int nt = 0; nt < 4; ++nt) {
      *(f32x4*)(dst + nt * 4) = acc0[nt];
      *(f32x4*)(dst + 16 + nt * 4) = acc1[nt];
    }
    *(f32x4*)(dst + 32) = sum0;
    *(f32x4*)(dst + 36) = sum1;
  }
  __syncthreads();
  if (half == 1) return;
  {
    const float* src = &cmb[(rw * 64 + lane) * 40];
#pragma unroll
    for (int nt = 0; nt < 4; ++nt) {
      acc0[nt] += *(const f32x4*)(src + nt * 4);
      acc1[nt] += *(const f32x4*)(src + 16 + nt * 4);
    }
    sum0 += *(const f32x4*)(src + 32);
    sum1 += *(const f32x4*)(src + 36);
  }

  if (jsCount == 1) {
#pragma unroll
    for (int g = 0; g < 2; ++g) {
      const f32x4* acc = g ? acc1 : acc0;
      const f32x4 sm = g ? sum1 : sum0;
#pragma unroll
      for (int reg = 0; reg < 4; ++reg) {
        const int row = i0 + rbase + g * 16 + quad * 4 + reg;
        const float ls = __shfl(sm[reg], quad * 16);
        const float il = ls > 0.f ? 1.f / ls : 0.f;
#pragma unroll
        for (int nt = 0; nt < 4; ++nt) {
          float v = acc[nt][reg] * il;
          v = v > 0.f ? v : expm1f(v);  // elu
          const long o = (long)(p & 3) * strideB + (long)row * rowStride + (p >> 2) * 64 + nt * 16 + lm;
          out1[o] = v;
        }
      }
    }
  } else {
    float* pAcc = partAcc + ((long)p * jsCount + js) * NN * 64;
    float* pSum = partSum + ((long)p * jsCount + js) * NN;
#pragma unroll
    for (int g = 0; g < 2; ++g) {
      const f32x4* acc = g ? acc1 : acc0;
      const f32x4 sm = g ? sum1 : sum0;
#pragma unroll
      for (int reg = 0; reg < 4; ++reg) {
        const int row = i0 + rbase + g * 16 + quad * 4 + reg;
#pragma unroll
        for (int nt = 0; nt < 4; ++nt) pAcc[(long)row * 64 + nt * 16 + lm] = acc[nt][reg];
        if (lm == 0) pSum[row] = sm[reg];
      }
    }
  }
}

// ---------------- layer-3a: fused js-combine + elu + image_feature store + partials ----
__global__ __launch_bounds__(256) void layer3a_k(
    const float* __restrict__ partAcc, const float* __restrict__ partSum,
    const float* __restrict__ W2, const float* __restrict__ a2,
    const unsigned char* __restrict__ pm, float* __restrict__ outImg,
    float* __restrict__ pOut /* [B][8][17] */, int JS) {
  const int bb = blockIdx.x, chunk = blockIdx.y, t = threadIdx.x;
  __shared__ float w2alo[64], w2ahi[64];
  __shared__ float W2s[64][17];
  __shared__ float v0[64];
  __shared__ float redc[4][17];
  if (t < 64) {
    float sl = 0.f, sh = 0.f;
#pragma unroll
    for (int c = 0; c < 16; ++c) {
      const float wv = W2[t * 16 + c];
      W2s[t][c] = wv;
      sl += wv * a2[c];
      sh += wv * a2[16 + c];
    }
    w2alo[t] = sl;
    w2ahi[t] = sh;
    float s = 0.f, l0 = 0.f;
    for (int js = 0; js < JS; ++js) {
      const long b = ((long)bb * JS + js) * NN;
      s += partAcc[b * 64 + t];
      l0 += partSum[b];
    }
    float v = s * (l0 > 0.f ? 1.f / l0 : 0.f);
    v0[t] = v > 0.f ? v : expm1f(v);
  }
  __syncthreads();

  float es = 0.f;
#pragma unroll 16
  for (int k = 0; k < 64; ++k) es += v0[k] * w2alo[k];

  const int j = chunk * 256 + t;
  float arow[64];
  {
    f32x4 v[16];
#pragma unroll
    for (int qq = 0; qq < 16; ++qq) v[qq] = (f32x4){0.f, 0.f, 0.f, 0.f};
    float s = 0.f;
    for (int js = 0; js < JS; ++js) {
      const long b = ((long)bb * JS + js) * NN;
      const float* src = partAcc + (b + j) * 64;
#pragma unroll
      for (int qq = 0; qq < 16; ++qq) v[qq] += *(const f32x4*)(src + qq * 4);
      s += partSum[b + j];
    }
    const float il = s > 0.f ? 1.f / s : 0.f;
    float* orow = outImg + ((long)bb * NN + j) * 64;
#pragma unroll
    for (int qq = 0; qq < 16; ++qq) {
      f32x4 r;
#pragma unroll
      for (int u = 0; u < 4; ++u) {
        float x = v[qq][u] * il;
        r[u] = x > 0.f ? x : expm1f(x);
        arow[qq * 4 + u] = r[u];
      }
      *(f32x4*)(orow + qq * 4) = r;
    }
  }

  float ed = 0.f;
#pragma unroll
  for (int k = 0; k < 64; ++k) ed += arow[k] * w2ahi[k];
  float e = es + ed;
  e = fmaxf(e, 0.2f * e);
  const float pv = pm[((long)(j >> 5) << 16) + (j & 31)] ? __expf(e) : 0.f;  // row 0 mask

  float acc[16];
#pragma unroll
  for (int c = 0; c < 16; ++c) {
    float wh = 0.f;
#pragma unroll
    for (int k = 0; k < 64; ++k) wh += arow[k] * W2s[k][c];
    acc[c] = pv * wh;
  }
  float lsum = pv;

#pragma unroll
  for (int off = 32; off > 0; off >>= 1) {
    lsum += __shfl_down(lsum, off);
#pragma unroll
    for (int c = 0; c < 16; ++c) acc[c] += __shfl_down(acc[c], off);
  }
  if ((t & 63) == 0) {
    const int wv = t >> 6;
#pragma unroll
    for (int c = 0; c < 16; ++c) redc[wv][c] = acc[c];
    redc[wv][16] = lsum;
  }
  __syncthreads();
  if (t < 17) {
    pOut[((long)bb * 8 + chunk) * 17 + t] =
        redc[0][t] + redc[1][t] + redc[2][t] + redc[3][t];
  }
}

// ---------------- layer-3b: sum 8 chunks, normalize + elu ----------------
__global__ __launch_bounds__(64) void layer3b_k(const float* __restrict__ pOut,
                                                float* __restrict__ outPre) {
  const int t = threadIdx.x;
  if (t >= 64) return;
  const int bb = t >> 4, c = t & 15;
  float a = 0.f, l = 0.f;
#pragma unroll
  for (int ch = 0; ch < 8; ++ch) {
    a += pOut[((long)bb * 8 + ch) * 17 + c];
    l += pOut[((long)bb * 8 + ch) * 17 + 16];
  }
  float v = a / l;
  v = v > 0.f ? v : expm1f(v);
  outPre[bb * 16 + c] = v;
}

// ---------------- host ----------------
extern "C" void kernel_launch(void* const* d_in, const int* in_sizes, int n_in,
                              void* d_out, int out_size, void* d_ws, size_t ws_size,
                              hipStream_t stream) {
  (void)in_sizes; (void)n_in; (void)out_size; (void)ws_size;
  constexpr int B = 4, N = NN, JS2 = 4, KS2 = 4;

  const float* slices = (const float*)d_in[0];
  const int* adj = (const int*)d_in[1];
  const float* Ws = (const float*)d_in[2];
  const float* As = (const float*)d_in[3];
  const float* W1 = (const float*)d_in[4];
  const float* a1 = (const float*)d_in[5];
  const float* W2 = (const float*)d_in[6];
  const float* a2 = (const float*)d_in[7];
  float* out = (float*)d_out;

  char* w = (char*)d_ws;
  size_t off = 0;
  auto alloc = [&](size_t bytes) {
    void* ptr = w + off;
    off += (bytes + 255) & ~(size_t)255;
    return ptr;
  };
  unsigned char* pm = (unsigned char*)alloc((size_t)64 * 65536);  // 4 MB kb-tiled mask
  __bf16* WsFh = (__bf16*)alloc((size_t)8 * 128 * 64 * 2);
  __bf16* WsFl = (__bf16*)alloc((size_t)8 * 128 * 64 * 2);
  __bf16* W1Fh = (__bf16*)alloc((size_t)512 * 64 * 2);
  __bf16* W1Fl = (__bf16*)alloc((size_t)512 * 64 * 2);
  f16* WhB1 = (f16*)alloc((size_t)32 * N * 64 * 2);  // 8 MB
  float* E1 = (float*)alloc((size_t)32 * N * 4);
  float* G1 = (float*)alloc((size_t)32 * N * 4);
  f16* F1 = (f16*)alloc((size_t)32 * N * 2);
  f16* H1 = (f16*)alloc((size_t)32 * N * 2);
  float* x = (float*)alloc((size_t)B * N * 512 * 4);  // 16 MB
  float* pC2 = (float*)alloc((size_t)B * KS2 * N * 64 * 4);  // 8 MB
  f16* WhB2 = (f16*)alloc((size_t)B * N * 64 * 2);
  float* E2 = (float*)alloc((size_t)B * N * 4);
  float* G2 = (float*)alloc((size_t)B * N * 4);
  f16* F2 = (f16*)alloc((size_t)B * N * 2);
  f16* H2 = (f16*)alloc((size_t)B * N * 2);
  float* pAcc2 = (float*)alloc((size_t)B * JS2 * N * 64 * 4);  // 8 MB
  float* pSum2 = (float*)alloc((size_t)B * JS2 * N * 4);
  float* pL3 = (float*)alloc((size_t)B * 8 * 17 * 4);

  prep_k<<<dim3(2432), dim3(256), 0, stream>>>(adj, pm, Ws, WsFh, WsFl, W1, W1Fh, W1Fl);

  // layer 1
  gemm_mfma_k<<<dim3(N / 32, 32, 1), dim3(128), 0, stream>>>(
      slices, WsFh, WsFl, As, WhB1, E1, G1, F1, H1, (float*)nullptr,
      128, 1, (long)N * 128);
  attn_k<<<dim3(N / 128, 1, 32), dim3(512), 0, stream>>>(
      WhB1, E1, G1, F1, H1, pm, x, 512, (long)N * 512,
      1, (float*)nullptr, (float*)nullptr);

  // layer 2
  gemm_mfma_k<<<dim3(N / 32, 4, KS2), dim3(128), 0, stream>>>(
      x, W1Fh, W1Fl, a1, (f16*)nullptr, (float*)nullptr, (float*)nullptr,
      (f16*)nullptr, (f16*)nullptr, pC2, 512, KS2, (long)N * 512);
  gemm_epi_k<<<dim3(N / 16, 4), dim3(256), 0, stream>>>(
      pC2, a1, WhB2, E2, G2, F2, H2, KS2);
  attn_k<<<dim3(N / 128, JS2, 4), dim3(512), 0, stream>>>(
      WhB2, E2, G2, F2, H2, pm, (float*)nullptr, 64, (long)N * 64,
      JS2, pAcc2, pSum2);

  // layer 3 (fused combine + image_feature store) + reduce
  layer3a_k<<<dim3(B, 8), dim3(256), 0, stream>>>(
      pAcc2, pSum2, W2, a2, pm, out, pL3, JS2);
  layer3b_k<<<dim3(1), dim3(64), 0, stream>>>(pL3, out + (size_t)B * N * 64);
}

// Round 15
// 160.278 us; speedup vs baseline: 4.2254x; 1.0744x over previous
//
#include <hip/hip_runtime.h>
#include <hip/hip_bf16.h>
#include <cstdint>

// GAT 3-layer pipeline, MI355X. B=4, N=2048, Fin=128, nhid=64, H=8, emb=64, nclass=16.
// fp32 tensors; d_out = [image_feature (4*2048*64) | pre (4*16)] fp32.
// Round 15: r14's attention kept (global masks, 2-tile staging — recovered r13); the
// r12 layer3a fusion reverted: it ran the 8MB partial-combine on 32 blocks (1/8 of the
// GPU) and cost +7us vs r11. Tail restored to r11's wide combine_k (512 blocks) +
// lightweight layer3a reading the 2MB img + layer3b.

#define NN 2048

typedef float f32x4 __attribute__((ext_vector_type(4)));
typedef __bf16 bf16x8 __attribute__((ext_vector_type(8)));
typedef _Float16 f16;
typedef _Float16 f16x8 __attribute__((ext_vector_type(8)));

__device__ __forceinline__ void gll16(const void* g, void* l) {
  __builtin_amdgcn_global_load_lds(
      (const __attribute__((address_space(1))) unsigned int*)g,
      (__attribute__((address_space(3))) unsigned int*)l, 16, 0, 0);
}

// ---------------- fused prep: adj->u8 kb-tiled plane, Ws/W1 -> bf16 hi/lo frags ----
// pm layout: [kb(64)][i(2048)][jb(32)] u8 (0xFF if edge) — 4 MB, tiles contiguous.
__global__ __launch_bounds__(256) void prep_k(
    const int* __restrict__ adj, unsigned char* __restrict__ pm,
    const float* __restrict__ Ws, __bf16* __restrict__ WsFh, __bf16* __restrict__ WsFl,
    const float* __restrict__ W1, __bf16* __restrict__ W1Fh, __bf16* __restrict__ W1Fl) {
  const int bx = blockIdx.x, t = threadIdx.x;
  if (bx < 2048) {
    const int i = bx;
#pragma unroll
    for (int jt = 0; jt < 8; ++jt) {
      const int j = jt * 256 + t;
      pm[((long)(j >> 5) << 16) + i * 32 + (j & 31)] =
          adj[(long)i * NN + j] > 0 ? 0xFFu : 0u;
    }
  } else if (bx < 2304) {
    const int idx = (bx - 2048) * 256 + t;  // 8 inst x 8192
    const int inst = idx >> 13;
    const int rem = idx & 8191;
    const int k = rem >> 6, n = rem & 63;
    const float v = Ws[(long)inst * 8192 + rem];
    const __bf16 vh = (__bf16)v;
    const int pos = ((k >> 5) * 4 + (n >> 4)) * 512 + (((k >> 3) & 3) * 16 + (n & 15)) * 8 + (k & 7);
    WsFh[(long)inst * 8192 + pos] = vh;
    WsFl[(long)inst * 8192 + pos] = (__bf16)(v - (float)vh);
  } else {
    const int idx = (bx - 2304) * 256 + t;  // 512 x 64
    const int k = idx >> 6, n = idx & 63;
    const float v = W1[idx];
    const __bf16 vh = (__bf16)v;
    const int pos = ((k >> 5) * 4 + (n >> 4)) * 512 + (((k >> 3) & 3) * 16 + (n & 15)) * 8 + (k & 7);
    W1Fh[pos] = vh;
    W1Fl[pos] = (__bf16)(v - (float)vh);
  }
}

// ---------------- MFMA GEMM (M rows, N=64). 128 thr, 32 rows/block. ----------------
struct GemmLd {
  float4 a0, a1;
  bf16x8 bh[4], bl[4];
};

__global__ __launch_bounds__(128) void gemm_mfma_k(
    const float* __restrict__ Aall, const __bf16* __restrict__ WFhi,
    const __bf16* __restrict__ WFlo, const float* __restrict__ avecAll,
    f16* __restrict__ WhBAll, float* __restrict__ Eo, float* __restrict__ Go,
    f16* __restrict__ Fo, f16* __restrict__ Ho, float* __restrict__ pC,
    int K, int KS, long aStrideB) {
  const int p = blockIdx.y;
  const int ks = blockIdx.z;
  const float* A = Aall + (long)(p & 3) * aStrideB;
  const long wfOff = (long)(p >> 2) * K * 64;
  const bf16x8* BhF = (const bf16x8*)(WFhi + wfOff);
  const bf16x8* BlF = (const bf16x8*)(WFlo + wfOff);

  const int t = threadIdx.x, lane = t & 63, wave = t >> 6;
  const int quad = lane >> 4, lm = lane & 15;
  const int i0w = blockIdx.x * 32 + wave * 16;
  const float* Arow = A + (long)(i0w + lm) * K;
  const int kBeg = ks * (K / KS), kEnd = kBeg + K / KS;

  f32x4 acc[4];
#pragma unroll
  for (int nt = 0; nt < 4; ++nt) acc[nt] = (f32x4){0.f, 0.f, 0.f, 0.f};

  auto LOAD = [&](GemmLd& L, int k0) {
    L.a0 = *(const float4*)(Arow + k0 + quad * 8);
    L.a1 = *(const float4*)(Arow + k0 + quad * 8 + 4);
    const int bbase = (k0 >> 5) * 256 + lane;
#pragma unroll
    for (int nt = 0; nt < 4; ++nt) {
      L.bh[nt] = BhF[bbase + nt * 64];
      L.bl[nt] = BlF[bbase + nt * 64];
    }
  };
  auto STEP = [&](const GemmLd& L) {
    const float av8[8] = {L.a0.x, L.a0.y, L.a0.z, L.a0.w, L.a1.x, L.a1.y, L.a1.z, L.a1.w};
    bf16x8 ah, al;
#pragma unroll
    for (int j = 0; j < 8; ++j) {
      const __bf16 h = (__bf16)av8[j];
      ah[j] = h;
      al[j] = (__bf16)(av8[j] - (float)h);
    }
#pragma unroll
    for (int nt = 0; nt < 4; ++nt) {
      acc[nt] = __builtin_amdgcn_mfma_f32_16x16x32_bf16(ah, L.bh[nt], acc[nt], 0, 0, 0);
      acc[nt] = __builtin_amdgcn_mfma_f32_16x16x32_bf16(al, L.bh[nt], acc[nt], 0, 0, 0);
      acc[nt] = __builtin_amdgcn_mfma_f32_16x16x32_bf16(ah, L.bl[nt], acc[nt], 0, 0, 0);
    }
  };

  GemmLd La, Lb;
  LOAD(La, kBeg);
  for (int k0 = kBeg; k0 < kEnd; k0 += 64) {
    LOAD(Lb, k0 + 32);
    STEP(La);
    LOAD(La, (k0 + 64 < kEnd) ? k0 + 64 : kBeg);
    STEP(Lb);
  }

  if (KS > 1) {
    float* pc = pC + ((long)(p * KS + ks) * NN) * 64;
#pragma unroll
    for (int reg = 0; reg < 4; ++reg) {
      const int row = i0w + quad * 4 + reg;
#pragma unroll
      for (int nt = 0; nt < 4; ++nt) pc[(long)row * 64 + nt * 16 + lm] = acc[nt][reg];
    }
    return;
  }

  const float* av = avecAll + (long)(p >> 2) * 128;
  f16* WhB = WhBAll + (long)p * NN * 64;
  float* E = Eo + (long)p * NN;
  float* G = Go + (long)p * NN;
  f16* F = Fo + (long)p * NN;
  f16* Hh = Ho + (long)p * NN;

  float alo[4], ahi[4];
#pragma unroll
  for (int nt = 0; nt < 4; ++nt) {
    alo[nt] = av[nt * 16 + lm];
    ahi[nt] = av[64 + nt * 16 + lm];
  }
#pragma unroll
  for (int reg = 0; reg < 4; ++reg) {
    float es = 0.f, ed = 0.f;
#pragma unroll
    for (int nt = 0; nt < 4; ++nt) {
      es += acc[nt][reg] * alo[nt];
      ed += acc[nt][reg] * ahi[nt];
    }
#pragma unroll
    for (int m = 1; m < 16; m <<= 1) {
      es += __shfl_xor(es, m);
      ed += __shfl_xor(ed, m);
    }
    if (lm == 0) {
      const int r = i0w + quad * 4 + reg;
      E[r] = __expf(es);
      G[r] = __expf(0.2f * es);
      F[r] = (f16)__expf(ed);
      Hh[r] = (f16)__expf(0.2f * ed);
    }
  }

  const int r0 = i0w + quad * 4;
  const long base = ((long)(r0 >> 5) * 4) * 512 + (((r0 >> 3) & 3) * 16 + lm) * 8 + (r0 & 7);
#pragma unroll
  for (int nt = 0; nt < 4; ++nt) {
    union { f16 h[4]; uint2 u; } pk;
#pragma unroll
    for (int q = 0; q < 4; ++q) pk.h[q] = (f16)acc[nt][q];
    *(uint2*)(WhB + base + nt * 512) = pk.u;
  }
}

// ---------------- layer-2 GEMM epilogue: sum KS partials -> E/G/F/H + WhB f16 ----
__global__ __launch_bounds__(256) void gemm_epi_k(
    const float* __restrict__ pC, const float* __restrict__ avec,
    f16* __restrict__ WhBAll, float* __restrict__ Eo, float* __restrict__ Go,
    f16* __restrict__ Fo, f16* __restrict__ Ho, int KS) {
  const int inst = blockIdx.y;
  const int t = threadIdx.x;
  const int row = blockIdx.x * 16 + (t >> 4);
  const int cg = t & 15;
  f32x4 c = (f32x4){0.f, 0.f, 0.f, 0.f};
  for (int ks = 0; ks < KS; ++ks)
    c += *(const f32x4*)(pC + (((long)(inst * KS + ks) * NN) + row) * 64 + cg * 4);
  float es = 0.f, ed = 0.f;
#pragma unroll
  for (int q = 0; q < 4; ++q) {
    const int n = cg * 4 + q;
    es += c[q] * avec[n];
    ed += c[q] * avec[64 + n];
  }
#pragma unroll
  for (int m = 1; m < 16; m <<= 1) {
    es += __shfl_xor(es, m);
    ed += __shfl_xor(ed, m);
  }
  if (cg == 0) {
    Eo[(long)inst * NN + row] = __expf(es);
    Go[(long)inst * NN + row] = __expf(0.2f * es);
    Fo[(long)inst * NN + row] = (f16)__expf(ed);
    Ho[(long)inst * NN + row] = (f16)__expf(0.2f * ed);
  }
  f16* WhB = WhBAll + (long)inst * NN * 64;
#pragma unroll
  for (int q = 0; q < 4; ++q) {
    const int n = cg * 4 + q;
    const int pos = ((row >> 5) * 4 + (n >> 4)) * 512 + (((row >> 3) & 3) * 16 + (n & 15)) * 8 + (row & 7);
    WhB[pos] = (f16)c[q];
  }
}

// ---------------- attention: LDS-staged B (2 tiles/barrier), global masks ----------
// 512 thr = 8 waves: rw = wave&3 (32 rows each, block = 128 rows), half = wave>>2
// (kb-half). Wave rw==0 of each half stages TWO 4KB B-tiles per step into an 8KB slot
// (double-buffered); masks are coalesced uint2 global loads (no LDS, no conflicts).
__global__ __launch_bounds__(512) void attn_k(
    const f16* __restrict__ WhBAll, const float* __restrict__ Eb,
    const float* __restrict__ Gb, const f16* __restrict__ Fb,
    const f16* __restrict__ Hb, const unsigned char* __restrict__ pm,
    float* __restrict__ out1, int rowStride, long strideB,
    int jsCount, float* __restrict__ partAcc, float* __restrict__ partSum) {
  const int p = blockIdx.z;
  const int js = blockIdx.y;
  const f16* WhB = WhBAll + (long)p * NN * 64;
  const float* E = Eb + (long)p * NN;
  const float* G = Gb + (long)p * NN;
  const f16* F = Fb + (long)p * NN;
  const f16* Hv = Hb + (long)p * NN;
  const int t = threadIdx.x, lane = t & 63, wave = t >> 6;
  const int rw = wave & 3, half = wave >> 2;
  const int quad = lane >> 4, lm = lane & 15;
  const int i0 = blockIdx.x * 128;
  const int rbase = rw * 32;
  const int span = 64 / jsCount;     // kb per js job
  const int nIter = span / 2;        // kb per half
  const int nStep = nIter / 2;       // 2 kb per step
  const int kbBeg = js * span + half * nIter;

  // LDS pool: [0,4K) F, [4K,8K) H, [8K,40K) rings (half*16K + slot*8K, slot = 2 B-tiles)
  __shared__ __align__(16) char pool[40960];
  f16* Fs = (f16*)pool;
  f16* Hs = (f16*)(pool + 4096);
  char* ring = pool + 8192 + half * 16384;

  const int r0g = i0 + rbase + lm, r1g = i0 + rbase + 16 + lm;
  const f16 e0 = (f16)E[r0g], g0 = (f16)G[r0g];
  const f16 e1 = (f16)E[r1g], g1 = (f16)G[r1g];
  f16x8 e0v, g0v, e1v, g1v;
#pragma unroll
  for (int j = 0; j < 8; ++j) { e0v[j] = e0; g0v[j] = g0; e1v[j] = e1; g1v[j] = g1; }

  f16x8 ones;
#pragma unroll
  for (int j = 0; j < 8; ++j) ones[j] = (lm == 0) ? (f16)1.0f : (f16)0.0f;

  // prologue staging: F/H (wave 0/1) + first 8KB B slot per half (rw==0 waves)
  if (wave == 0) {
#pragma unroll
    for (int c = 0; c < 4; ++c) gll16((const char*)F + c * 1024 + lane * 16, pool + c * 1024);
  } else if (wave == 1) {
#pragma unroll
    for (int c = 0; c < 4; ++c) gll16((const char*)Hv + c * 1024 + lane * 16, pool + 4096 + c * 1024);
  }
  if (rw == 0) {
    const char* gB = (const char*)WhB + (long)kbBeg * 4096;
#pragma unroll
    for (int c = 0; c < 8; ++c) gll16(gB + c * 1024 + lane * 16, ring + c * 1024);
  }
  __syncthreads();

  f32x4 acc0[4], acc1[4], sum0, sum1;
#pragma unroll
  for (int nt = 0; nt < 4; ++nt) {
    acc0[nt] = (f32x4){0.f, 0.f, 0.f, 0.f};
    acc1[nt] = (f32x4){0.f, 0.f, 0.f, 0.f};
  }
  sum0 = (f32x4){0.f, 0.f, 0.f, 0.f};
  sum1 = (f32x4){0.f, 0.f, 0.f, 0.f};

  const unsigned char* mp0 = pm + (long)(i0 + rbase + lm) * 32 + quad * 8;
  const unsigned char* mp1 = pm + (long)(i0 + rbase + 16 + lm) * 32 + quad * 8;

  for (int s = 0; s < nStep; ++s) {
    if (rw == 0 && s + 1 < nStep) {  // prefetch next 2 tiles into other slot
      char* dst = ring + ((s + 1) & 1) * 8192;
      const char* gB = (const char*)WhB + (long)(kbBeg + (s + 1) * 2) * 4096;
#pragma unroll
      for (int c = 0; c < 8; ++c) gll16(gB + c * 1024 + lane * 16, dst + c * 1024);
    }
    const char* slot = ring + (s & 1) * 8192;
#pragma unroll
    for (int u = 0; u < 2; ++u) {
      const int kb = kbBeg + s * 2 + u;
      const char* bt = slot + u * 4096;
      const uint2 m0 = *(const uint2*)(mp0 + ((long)kb << 16));
      const uint2 m1 = *(const uint2*)(mp1 + ((long)kb << 16));
      const f16x8 F8 = *(const f16x8*)(Fs + kb * 32 + quad * 8);
      const f16x8 H8 = *(const f16x8*)(Hs + kb * 32 + quad * 8);

      union { f16x8 v; uint4 u4; } A0, A1;
      A0.v = __builtin_elementwise_max(e0v * F8, g0v * H8);
      A1.v = __builtin_elementwise_max(e1v * F8, g1v * H8);
      A0.u4.x &= __builtin_amdgcn_perm(0u, m0.x, 0x01010000u);
      A0.u4.y &= __builtin_amdgcn_perm(0u, m0.x, 0x03030202u);
      A0.u4.z &= __builtin_amdgcn_perm(0u, m0.y, 0x01010000u);
      A0.u4.w &= __builtin_amdgcn_perm(0u, m0.y, 0x03030202u);
      A1.u4.x &= __builtin_amdgcn_perm(0u, m1.x, 0x01010000u);
      A1.u4.y &= __builtin_amdgcn_perm(0u, m1.x, 0x03030202u);
      A1.u4.z &= __builtin_amdgcn_perm(0u, m1.y, 0x01010000u);
      A1.u4.w &= __builtin_amdgcn_perm(0u, m1.y, 0x03030202u);

#pragma unroll
      for (int nt = 0; nt < 4; ++nt) {
        const f16x8 bfr = *(const f16x8*)(bt + (nt * 64 + lane) * 16);
        acc0[nt] = __builtin_amdgcn_mfma_f32_16x16x32_f16(A0.v, bfr, acc0[nt], 0, 0, 0);
        acc1[nt] = __builtin_amdgcn_mfma_f32_16x16x32_f16(A1.v, bfr, acc1[nt], 0, 0, 0);
      }
      sum0 = __builtin_amdgcn_mfma_f32_16x16x32_f16(A0.v, ones, sum0, 0, 0, 0);
      sum1 = __builtin_amdgcn_mfma_f32_16x16x32_f16(A1.v, ones, sum1, 0, 0, 0);
    }
    __syncthreads();
  }

  // ---- combine the two kb-halves via LDS (overlay pool) ----
  float* cmb = (float*)pool;
  if (half == 1) {
    float* dst = &cmb[(rw * 64 + lane) * 40];
#pragma unroll
    for (int nt = 0; nt < 4; ++nt) {
      *(f32x4*)(dst + nt * 4) = acc0[nt];
      *(f32x4*)(dst + 16 + nt * 4) = acc1[nt];
    }
    *(f32x4*)(dst + 32) = sum0;
    *(f32x4*)(dst + 36) = sum1;
  }
  __syncthreads();
  if (half == 1) return;
  {
    const float* src = &cmb[(rw * 64 + lane) * 40];
#pragma unroll
    for (int nt = 0; nt < 4; ++nt) {
      acc0[nt] += *(const f32x4*)(src + nt * 4);
      acc1[nt] += *(const f32x4*)(src + 16 + nt * 4);
    }
    sum0 += *(const f32x4*)(src + 32);
    sum1 += *(const f32x4*)(src + 36);
  }

  if (jsCount == 1) {
#pragma unroll
    for (int g = 0; g < 2; ++g) {
      const f32x4* acc = g ? acc1 : acc0;
      const f32x4 sm = g ? sum1 : sum0;
#pragma unroll
      for (int reg = 0; reg < 4; ++reg) {
        const int row = i0 + rbase + g * 16 + quad * 4 + reg;
        const float ls = __shfl(sm[reg], quad * 16);
        const float il = ls > 0.f ? 1.f / ls : 0.f;
#pragma unroll
        for (int nt = 0; nt < 4; ++nt) {
          float v = acc[nt][reg] * il;
          v = v > 0.f ? v : expm1f(v);  // elu
          const long o = (long)(p & 3) * strideB + (long)row * rowStride + (p >> 2) * 64 + nt * 16 + lm;
          out1[o] = v;
        }
      }
    }
  } else {
    float* pAcc = partAcc + ((long)p * jsCount + js) * NN * 64;
    float* pSum = partSum + ((long)p * jsCount + js) * NN;
#pragma unroll
    for (int g = 0; g < 2; ++g) {
      const f32x4* acc = g ? acc1 : acc0;
      const f32x4 sm = g ? sum1 : sum0;
#pragma unroll
      for (int reg = 0; reg < 4; ++reg) {
        const int row = i0 + rbase + g * 16 + quad * 4 + reg;
#pragma unroll
        for (int nt = 0; nt < 4; ++nt) pAcc[(long)row * 64 + nt * 16 + lm] = acc[nt][reg];
        if (lm == 0) pSum[row] = sm[reg];
      }
    }
  }
}

// ---------------- combine j-split partials: normalize + elu + dual write (512 blocks) ----
__global__ __launch_bounds__(256) void combine_k(const float* __restrict__ partAcc,
                                                 const float* __restrict__ partSum,
                                                 float* __restrict__ img,
                                                 float* __restrict__ out, int JS) {
  const long idx = (long)blockIdx.x * 256 + threadIdx.x;
  const int cg = idx & 15;
  const int row = (int)((idx >> 4) & (NN - 1));
  const int inst = (int)(idx >> 15);
  f32x4 v = (f32x4){0.f, 0.f, 0.f, 0.f};
  float s = 0.f;
  for (int js = 0; js < JS; ++js) {
    const long b = ((long)inst * JS + js) * NN;
    v += *(const f32x4*)(partAcc + (b + row) * 64 + cg * 4);
    s += partSum[b + row];
  }
  const float il = s > 0.f ? 1.f / s : 0.f;
  f32x4 r;
#pragma unroll
  for (int q = 0; q < 4; ++q) {
    float x = v[q] * il;
    r[q] = x > 0.f ? x : expm1f(x);
  }
  const long o = ((long)inst * NN + row) * 64 + cg * 4;
  *(f32x4*)(img + o) = r;
  *(f32x4*)(out + o) = r;
}

// ---------------- layer-3a: on-the-fly Wh3, j-split partials (grid B x 8) ----------------
__global__ __launch_bounds__(256) void layer3a_k(
    const float* __restrict__ img, const float* __restrict__ W2,
    const float* __restrict__ a2, const unsigned char* __restrict__ pm,
    float* __restrict__ pOut /* [B][8][17] */) {
  const int bb = blockIdx.x, chunk = blockIdx.y, t = threadIdx.x;
  const float* A = img + (long)bb * NN * 64;
  __shared__ float w2alo[64], w2ahi[64];
  __shared__ float W2s[64][17];
  __shared__ float redc[4][17];
  if (t < 64) {
    float sl = 0.f, sh = 0.f;
#pragma unroll
    for (int c = 0; c < 16; ++c) {
      const float wv = W2[t * 16 + c];
      W2s[t][c] = wv;
      sl += wv * a2[c];
      sh += wv * a2[16 + c];
    }
    w2alo[t] = sl;
    w2ahi[t] = sh;
  }
  __syncthreads();

  float es = 0.f;
#pragma unroll 16
  for (int k = 0; k < 64; ++k) es += A[k] * w2alo[k];

  const int j = chunk * 256 + t;
  float arow[64];
#pragma unroll
  for (int q = 0; q < 16; ++q) *(f32x4*)(arow + q * 4) = *(const f32x4*)(A + (long)j * 64 + q * 4);
  float ed = 0.f;
#pragma unroll
  for (int k = 0; k < 64; ++k) ed += arow[k] * w2ahi[k];
  float e = es + ed;
  e = fmaxf(e, 0.2f * e);
  const float pv = pm[((long)(j >> 5) << 16) + (j & 31)] ? __expf(e) : 0.f;  // row 0 mask

  float acc[16];
#pragma unroll
  for (int c = 0; c < 16; ++c) {
    float wh = 0.f;
#pragma unroll
    for (int k = 0; k < 64; ++k) wh += arow[k] * W2s[k][c];
    acc[c] = pv * wh;
  }
  float lsum = pv;

#pragma unroll
  for (int off = 32; off > 0; off >>= 1) {
    lsum += __shfl_down(lsum, off);
#pragma unroll
    for (int c = 0; c < 16; ++c) acc[c] += __shfl_down(acc[c], off);
  }
  if ((t & 63) == 0) {
    const int wv = t >> 6;
#pragma unroll
    for (int c = 0; c < 16; ++c) redc[wv][c] = acc[c];
    redc[wv][16] = lsum;
  }
  __syncthreads();
  if (t < 17) {
    pOut[((long)bb * 8 + chunk) * 17 + t] =
        redc[0][t] + redc[1][t] + redc[2][t] + redc[3][t];
  }
}

// ---------------- layer-3b: sum 8 chunks, normalize + elu ----------------
__global__ __launch_bounds__(64) void layer3b_k(const float* __restrict__ pOut,
                                                float* __restrict__ outPre) {
  const int t = threadIdx.x;
  if (t >= 64) return;
  const int bb = t >> 4, c = t & 15;
  float a = 0.f, l = 0.f;
#pragma unroll
  for (int ch = 0; ch < 8; ++ch) {
    a += pOut[((long)bb * 8 + ch) * 17 + c];
    l += pOut[((long)bb * 8 + ch) * 17 + 16];
  }
  float v = a / l;
  v = v > 0.f ? v : expm1f(v);
  outPre[bb * 16 + c] = v;
}

// ---------------- host ----------------
extern "C" void kernel_launch(void* const* d_in, const int* in_sizes, int n_in,
                              void* d_out, int out_size, void* d_ws, size_t ws_size,
                              hipStream_t stream) {
  (void)in_sizes; (void)n_in; (void)out_size; (void)ws_size;
  constexpr int B = 4, N = NN, JS2 = 4, KS2 = 4;

  const float* slices = (const float*)d_in[0];
  const int* adj = (const int*)d_in[1];
  const float* Ws = (const float*)d_in[2];
  const float* As = (const float*)d_in[3];
  const float* W1 = (const float*)d_in[4];
  const float* a1 = (const float*)d_in[5];
  const float* W2 = (const float*)d_in[6];
  const float* a2 = (const float*)d_in[7];
  float* out = (float*)d_out;

  char* w = (char*)d_ws;
  size_t off = 0;
  auto alloc = [&](size_t bytes) {
    void* ptr = w + off;
    off += (bytes + 255) & ~(size_t)255;
    return ptr;
  };
  unsigned char* pm = (unsigned char*)alloc((size_t)64 * 65536);  // 4 MB kb-tiled mask
  __bf16* WsFh = (__bf16*)alloc((size_t)8 * 128 * 64 * 2);
  __bf16* WsFl = (__bf16*)alloc((size_t)8 * 128 * 64 * 2);
  __bf16* W1Fh = (__bf16*)alloc((size_t)512 * 64 * 2);
  __bf16* W1Fl = (__bf16*)alloc((size_t)512 * 64 * 2);
  f16* WhB1 = (f16*)alloc((size_t)32 * N * 64 * 2);  // 8 MB
  float* E1 = (float*)alloc((size_t)32 * N * 4);
  float* G1 = (float*)alloc((size_t)32 * N * 4);
  f16* F1 = (f16*)alloc((size_t)32 * N * 2);
  f16* H1 = (f16*)alloc((size_t)32 * N * 2);
  float* x = (float*)alloc((size_t)B * N * 512 * 4);  // 16 MB
  float* pC2 = (float*)alloc((size_t)B * KS2 * N * 64 * 4);  // 8 MB
  f16* WhB2 = (f16*)alloc((size_t)B * N * 64 * 2);
  float* E2 = (float*)alloc((size_t)B * N * 4);
  float* G2 = (float*)alloc((size_t)B * N * 4);
  f16* F2 = (f16*)alloc((size_t)B * N * 2);
  f16* H2 = (f16*)alloc((size_t)B * N * 2);
  float* img = (float*)alloc((size_t)B * N * 64 * 4);  // 2 MB
  float* pAcc2 = (float*)alloc((size_t)B * JS2 * N * 64 * 4);  // 8 MB
  float* pSum2 = (float*)alloc((size_t)B * JS2 * N * 4);
  float* pL3 = (float*)alloc((size_t)B * 8 * 17 * 4);

  prep_k<<<dim3(2432), dim3(256), 0, stream>>>(adj, pm, Ws, WsFh, WsFl, W1, W1Fh, W1Fl);

  // layer 1
  gemm_mfma_k<<<dim3(N / 32, 32, 1), dim3(128), 0, stream>>>(
      slices, WsFh, WsFl, As, WhB1, E1, G1, F1, H1, (float*)nullptr,
      128, 1, (long)N * 128);
  attn_k<<<dim3(N / 128, 1, 32), dim3(512), 0, stream>>>(
      WhB1, E1, G1, F1, H1, pm, x, 512, (long)N * 512,
      1, (float*)nullptr, (float*)nullptr);

  // layer 2
  gemm_mfma_k<<<dim3(N / 32, 4, KS2), dim3(128), 0, stream>>>(
      x, W1Fh, W1Fl, a1, (f16*)nullptr, (float*)nullptr, (float*)nullptr,
      (f16*)nullptr, (f16*)nullptr, pC2, 512, KS2, (long)N * 512);
  gemm_epi_k<<<dim3(N / 16, 4), dim3(256), 0, stream>>>(
      pC2, a1, WhB2, E2, G2, F2, H2, KS2);
  attn_k<<<dim3(N / 128, JS2, 4), dim3(512), 0, stream>>>(
      WhB2, E2, G2, F2, H2, pm, (float*)nullptr, 64, (long)N * 64,
      JS2, pAcc2, pSum2);
  combine_k<<<dim3(B * N * 16 / 256), dim3(256), 0, stream>>>(pAcc2, pSum2, img, out, JS2);

  // layer 3
  layer3a_k<<<dim3(B, 8), dim3(256), 0, stream>>>(img, W2, a2, pm, pL3);
  layer3b_k<<<dim3(1), dim3(64), 0, stream>>>(pL3, out + (size_t)B * N * 64);
}